// Round 6
// baseline (245.164 us; speedup 1.0000x reference)
//
#include <hip/hip_runtime.h>
#include <hip/hip_bf16.h>

// Problem constants
#define S_   3
#define B_   4096
#define DIN_ 1024
#define H1_  512
#define H2_  384
#define H3_  256
#define D_   128
#define K_   512
#define C_   3
#define INV_T 10.0f          // 1/TEMP
#define EPS_  1e-12f
#define EXP10 22026.465794806718f   // exp(1/T), diag(refl) analytically

typedef float f32x4 __attribute__((ext_vector_type(4)));
typedef short bf16x8 __attribute__((ext_vector_type(8)));

__device__ __forceinline__ unsigned short f2bf(float f) {
  unsigned int u = __float_as_uint(f);
  u = (u + 0x7FFF + ((u >> 16) & 1)) >> 16;   // round-to-nearest-even
  return (unsigned short)u;
}

// async 16B-per-lane global -> LDS (wave-uniform base + lane*16 on both sides)
__device__ __forceinline__ void gl2lds16(const unsigned short* g, unsigned short* l) {
  __builtin_amdgcn_global_load_lds(
      (const __attribute__((address_space(1))) void*)g,
      (__attribute__((address_space(3))) void*)l, 16, 0, 0);
}

// ---------------- reduction helpers ----------------
__device__ __forceinline__ float waveReduceSum(float v) {
#pragma unroll
  for (int off = 32; off > 0; off >>= 1) v += __shfl_down(v, off, 64);
  return v;
}

__device__ __forceinline__ float waveXorSum(float v) {
#pragma unroll
  for (int off = 32; off > 0; off >>= 1) v += __shfl_xor(v, off, 64);
  return v;
}

// ------- fused prep: x cvt + weight transposes (w4 plain) + cb norms + qw1^T -----
__global__ __launch_bounds__(256) void prep_kernel(
    const float* __restrict__ x, unsigned short* __restrict__ xb,
    const float* __restrict__ w1, unsigned short* __restrict__ wt1,
    const float* __restrict__ w2, unsigned short* __restrict__ wt2,
    const float* __restrict__ w3, unsigned short* __restrict__ wt3,
    const float* __restrict__ w4, unsigned short* __restrict__ w4tb,
    const float* __restrict__ cb, float* __restrict__ cbn2,
    float* __restrict__ cbsumP, unsigned short* __restrict__ cbb,
    const float* __restrict__ qw1, unsigned short* __restrict__ qw1tb) {
  __shared__ float tt[32][33];
  __shared__ float invn[64];
  const int t = threadIdx.x;
  int blk = blockIdx.x;
  const int NCVT = (S_ * B_ * DIN_) / 1024;   // 12288
  if (blk < NCVT) {
    int i = (blk * 256 + t) * 4;
    float4 v = *(const float4*)(x + i);
    xb[i + 0] = f2bf(v.x); xb[i + 1] = f2bf(v.y);
    xb[i + 2] = f2bf(v.z); xb[i + 3] = f2bf(v.w);
    return;
  }
  blk -= NCVT;
  const int NT = 1536 + 576 + 288 + 96;       // 2496 transpose blocks
  if (blk >= NT) {
    int cblk = blk - NT;
    if (cblk < 24) {
      // ---- codebook norms + bf16 convert + column-sum partials ----
      const int m = cblk >> 3;
      const int k0 = (cblk & 7) * 64;
      const int w = t >> 6, lane = t & 63;
      for (int r = w * 16; r < w * 16 + 16; r++) {
        int k = k0 + r;
        float2 v = *(const float2*)(cb + ((size_t)m * K_ + k) * D_ + lane * 2);
        unsigned short* crow = cbb + ((size_t)m * K_ + k) * D_;
        crow[lane * 2 + 0] = f2bf(v.x);
        crow[lane * 2 + 1] = f2bf(v.y);
        float n2 = waveXorSum(v.x * v.x + v.y * v.y);
        if (lane == 0) {
          cbn2[m * K_ + k] = n2;
          invn[r] = 1.0f / fmaxf(sqrtf(n2), EPS_);
        }
      }
      __syncthreads();
      if (t < D_) {
        float acc = 0.0f;
        for (int r = 0; r < 64; r++)
          acc += cb[((size_t)m * K_ + k0 + r) * D_ + t] * invn[r];
        cbsumP[(size_t)cblk * D_ + t] = acc;
      }
      return;
    }
    // ---- qw1^T bf16 (d-major): 16 blocks of 32x32 ----
    cblk -= 24;                                // [0,16)
    const int kx = cblk & 3, ny = cblk >> 2;
    const int k0 = kx * 32, n0 = ny * 32;
    const int tx = t & 31, ty = t >> 5;
#pragma unroll
    for (int i = 0; i < 4; i++)
      tt[ty + 8 * i][tx] = qw1[(size_t)(k0 + ty + 8 * i) * D_ + n0 + tx];
    __syncthreads();
#pragma unroll
    for (int i = 0; i < 4; i++)
      qw1tb[(size_t)(n0 + ty + 8 * i) * D_ + k0 + tx] = f2bf(tt[tx][ty + 8 * i]);
    return;
  }
  const float* W; unsigned short* Wt; int K, N; int plain = 0;
  if (blk < 1536) { W = w1; Wt = wt1; K = DIN_; N = H1_; }
  else {
    blk -= 1536;
    if (blk < 576) { W = w2; Wt = wt2; K = H1_; N = H2_; }
    else {
      blk -= 576;
      if (blk < 288) { W = w3; Wt = wt3; K = H2_; N = H3_; }
      else { blk -= 288; W = w4; Wt = w4tb; K = H3_; N = D_; plain = 1; }
    }
  }
  const int kx_n = K / 32, ny_n = N / 32;
  const int kx = blk % kx_n;
  const int ny = (blk / kx_n) % ny_n;
  const int s  = blk / (kx_n * ny_n);
  const int k0 = kx * 32, n0 = ny * 32;
  const int tx = t & 31, ty = t >> 5;        // 32 x 8
  const float* Ws = W + (size_t)s * K * N;
  const int nb = N >> 7, kb = K >> 6;
#pragma unroll
  for (int i = 0; i < 4; i++)
    tt[ty + 8 * i][tx] = Ws[(size_t)(k0 + ty + 8 * i) * N + n0 + tx];
  __syncthreads();
  const int k = k0 + tx;
  if (plain) {
    // w4^T: [s][n][k] plain bf16 for direct fragment loads
#pragma unroll
    for (int i = 0; i < 4; i++) {
      int n = n0 + ty + 8 * i;
      Wt[((size_t)(s * D_ + n)) * H3_ + k] = f2bf(tt[tx][ty + 8 * i]);
    }
  } else {
    const int kt = k >> 6, ksl = (k >> 5) & 1;
#pragma unroll
    for (int i = 0; i < 4; i++) {
      int n = n0 + ty + 8 * i;
      size_t dst = ((size_t)(s * nb + (n >> 7)) * kb + kt) * 8192 +
                   (size_t)ksl * 4096 + (size_t)(n & 127) * 32 + (k & 31);
      Wt[dst] = f2bf(tt[tx][ty + 8 * i]);
    }
  }
}

// ---------------- LDS-staged MFMA GEMM, BK=64, async B via global_load_lds -------
__global__ __launch_bounds__(256) void gemm_lds_kernel(
    const unsigned short* __restrict__ A, const unsigned short* __restrict__ Wsw,
    const float* __restrict__ bias, void* __restrict__ Y,
    int K, int N, int relu, int out_f32) {
  const int t = threadIdx.x;
  const int lane = t & 63;
  const int w = t >> 6;
  const int ln = lane & 15, q = lane >> 4;
  const int wm = w >> 1, wn = w & 1;
  const int n0 = blockIdx.x * 128;
  const int mblk = blockIdx.y;
  const int s = mblk >> 6;                  // 4096/64 = 64 m-blocks per source
  const int m0 = mblk * 64;
  const int nb = N >> 7, kb = K >> 6;

  const unsigned short* Ag = A + (size_t)m0 * K;
  const unsigned short* Bt = Wsw + ((size_t)(s * nb + blockIdx.x) * kb) * 8192;
  const float* bs = bias + (size_t)s * N;

  __shared__ unsigned short Asm[2 * 64 * 32];     // 8 KB (two 32-k halves)
  __shared__ unsigned short Bsm[2 * 8192];        // 32 KB double buffer

  const int arow0 = t >> 3, ak8 = t & 7;
  const int aL0 = (ak8 >> 2) * 2048 + arow0 * 32 + (ak8 & 3) * 8;
  const size_t gA0 = (size_t)arow0 * K + ak8 * 8;

  // preload A regs (tile 0) + issue async B tile 0
  bf16x8 ra0 = *(const bf16x8*)(Ag + gA0);
  bf16x8 ra1 = *(const bf16x8*)(Ag + gA0 + (size_t)32 * K);
#pragma unroll
  for (int p = 0; p < 4; p++)
    gl2lds16(Bt + (size_t)(p * 256 + t) * 8, &Bsm[(size_t)(p * 256 + t) * 8]);

  f32x4 acc[2][4];
#pragma unroll
  for (int i = 0; i < 2; i++)
#pragma unroll
    for (int j = 0; j < 4; j++) acc[i][j] = (f32x4){0.f, 0.f, 0.f, 0.f};

  for (int kt = 0; kt < kb; kt++) {
    *(bf16x8*)&Asm[aL0] = ra0;
    *(bf16x8*)&Asm[aL0 + 1024] = ra1;
    __syncthreads();                       // drains vmcnt: B tile kt complete
    const unsigned short* Bcur = &Bsm[(kt & 1) * 8192];
    if (kt + 1 < kb) {
      const unsigned short* Bn = Bt + (size_t)(kt + 1) * 8192;
      unsigned short* Bd = &Bsm[((kt + 1) & 1) * 8192];
#pragma unroll
      for (int p = 0; p < 4; p++)
        gl2lds16(Bn + (size_t)(p * 256 + t) * 8, Bd + (size_t)(p * 256 + t) * 8);
      const size_t g = gA0 + (size_t)(kt + 1) * 64;
      ra0 = *(const bf16x8*)(Ag + g);
      ra1 = *(const bf16x8*)(Ag + g + (size_t)32 * K);
    }
    bf16x8 af[2][2], bf[4][2];
#pragma unroll
    for (int ti = 0; ti < 2; ti++)
#pragma unroll
      for (int ksl = 0; ksl < 2; ksl++)
        af[ti][ksl] = *(const bf16x8*)&Asm[ksl * 2048 + (wm * 32 + ti * 16 + ln) * 32 + q * 8];
#pragma unroll
    for (int tj = 0; tj < 4; tj++)
#pragma unroll
      for (int ksl = 0; ksl < 2; ksl++)
        bf[tj][ksl] = *(const bf16x8*)&Bcur[ksl * 4096 + (wn * 64 + tj * 16 + ln) * 32 + q * 8];
#pragma unroll
    for (int ksl = 0; ksl < 2; ksl++)
#pragma unroll
      for (int ti = 0; ti < 2; ti++)
#pragma unroll
        for (int tj = 0; tj < 4; tj++)
          acc[ti][tj] = __builtin_amdgcn_mfma_f32_16x16x32_bf16(af[ti][ksl], bf[tj][ksl], acc[ti][tj], 0, 0, 0);
    __syncthreads();
  }

#pragma unroll
  for (int ti = 0; ti < 2; ti++)
#pragma unroll
    for (int tj = 0; tj < 4; tj++) {
      const int cc = n0 + wn * 64 + tj * 16 + ln;
      const float bv = bs[cc];
#pragma unroll
      for (int reg = 0; reg < 4; reg++) {
        const int r = m0 + wm * 32 + ti * 16 + q * 4 + reg;
        float v = acc[ti][tj][reg] + bv;
        if (relu) v = fmaxf(v, 0.0f);
        if (out_f32) ((float*)Y)[(size_t)r * N + cc] = v;
        else ((unsigned short*)Y)[(size_t)r * N + cc] = f2bf(v);
      }
    }
}

// -------- mega-fused: layer-4 GEMM -> MFMA score -> softmax+fuse -> VQ -> norm ----
// 8 batch rows per block, 512 blocks (2 blocks/CU), 512 threads (8 waves).
// Wave w owns batch row w in all row-parallel phases -> most phases are
// wave-local (no barrier). MFMA tiles are 16-row with the upper half padded;
// pad rows produce garbage outputs that are discarded (MFMA rows independent).
__global__ __launch_bounds__(512) void l4vq_kernel(
    const unsigned short* __restrict__ h3b, const unsigned short* __restrict__ w4tb,
    const float* __restrict__ b4, const unsigned short* __restrict__ qw1tb,
    const float* __restrict__ qb1, const float* __restrict__ qw2,
    const float* __restrict__ cb, const unsigned short* __restrict__ cbb,
    const float* __restrict__ cbn2,
    unsigned short* __restrict__ zb, float* __restrict__ pos) {
  const int b0 = blockIdx.x * 8;
  const int t = threadIdx.x;
  const int w = t >> 6, lane = t & 63;
  const int ln = lane & 15, q = lane >> 4;

  __shared__ unsigned short h3s[32][264]; // h3 rows r=s*8+bi (24 valid; 8 pad) 16.9K
  __shared__ float e[24][D_];             // emb rows f32                      12K
  __shared__ unsigned short ebb[32][136]; // emb rows bf16 (24 valid; 8 pad)   8.7K
  __shared__ float qf[8][D_];             // fused -> z1                       4K
  __shared__ float resv[8][D_];           // residual f32                      4K
  __shared__ unsigned short resb[16][136];// residual bf16 (8 valid; 8 pad)    4.25K
  __shared__ float red2[8][24];
  __shared__ float sc[24];
  __shared__ float candd[8][16];
  __shared__ int candk[8][16];

  // qw1^T fragments for this wave's 16 score-cols (global, L2-hot)
  bf16x8 bq[4];
  {
    const unsigned short* qp = qw1tb + (size_t)(w * 16 + ln) * D_;
#pragma unroll
    for (int ks = 0; ks < 4; ks++)
      bq[ks] = *(const bf16x8*)(qp + ks * 32 + q * 8);
  }

  // ---- stage h3 rows (24 x 256 bf16 = 768 fragments) ----
#pragma unroll
  for (int p = 0; p < 2; p++) {
    int f = p * 512 + t;
    if (f < 768) {
      int r = f >> 5, kf = f & 31;
      int s = r >> 3, bi = r & 7;
      *(bf16x8*)&h3s[r][kf * 8] =
          *(const bf16x8*)(h3b + ((size_t)(s * B_ + b0 + bi)) * H3_ + kf * 8);
    }
  }
  __syncthreads();

  // ---- layer-4 GEMM: emb[s*8+rr][col], col = w*16+ln; rows 8-15 of each tile pad
  {
    const int col = w * 16 + ln;
#pragma unroll
    for (int s = 0; s < 3; s++) {
      f32x4 oacc = (f32x4){0.f, 0.f, 0.f, 0.f};
      const unsigned short* wp = w4tb + ((size_t)(s * D_ + col)) * H3_;
#pragma unroll
      for (int ks = 0; ks < 8; ks++) {
        bf16x8 bfrag = *(const bf16x8*)(wp + ks * 32 + q * 8);
        bf16x8 afrag = *(const bf16x8*)&h3s[s * 8 + ln][ks * 32 + q * 8];
        oacc = __builtin_amdgcn_mfma_f32_16x16x32_bf16(afrag, bfrag, oacc, 0, 0, 0);
      }
      if (q < 2) {
        const float bv = b4[s * D_ + col];
#pragma unroll
        for (int reg = 0; reg < 4; reg++) {
          int rr = q * 4 + reg;                 // 0..7
          float v = oacc[reg] + bv;
          e[s * 8 + rr][col] = v;
          ebb[s * 8 + rr][col] = f2bf(v);
        }
      }
    }
  }
  __syncthreads();

  // ---- attention scores via MFMA: 2 row-tiles of 16 (rows 24-31 pad) ----
  {
    f32x4 sacc[2];
#pragma unroll
    for (int rt = 0; rt < 2; rt++) sacc[rt] = (f32x4){0.f, 0.f, 0.f, 0.f};
#pragma unroll
    for (int ks = 0; ks < 4; ks++) {
#pragma unroll
      for (int rt = 0; rt < 2; rt++) {
        bf16x8 a = *(const bf16x8*)&ebb[rt * 16 + ln][ks * 32 + q * 8];
        sacc[rt] = __builtin_amdgcn_mfma_f32_16x16x32_bf16(a, bq[ks], sacc[rt], 0, 0, 0);
      }
    }
    const int col = w * 16 + ln;
    const float qb = qb1[col], q2v = qw2[col];
#pragma unroll
    for (int rt = 0; rt < 2; rt++)
#pragma unroll
      for (int reg = 0; reg < 4; reg++) {
        int rr = rt * 16 + q * 4 + reg;
        float v = tanhf(sacc[rt][reg] + qb) * q2v;
#pragma unroll
        for (int off = 8; off > 0; off >>= 1) v += __shfl_xor(v, off, 16);
        if (rr < 24 && ln == 0) red2[w][rr] = v;
      }
  }
  __syncthreads();
  if (t < 24) {
    float s = 0.f;
#pragma unroll
    for (int ww = 0; ww < 8; ww++) s += red2[ww][t];
    sc[t] = s;                                 // sc[r], r = s*8+bi
  }
  __syncthreads();

  // ---- softmax over sources + fuse: wave w owns row w, lane owns 2 cols ----
  {
    float s0 = sc[w], s1 = sc[8 + w], s2 = sc[16 + w];
    float mx = fmaxf(s0, fmaxf(s1, s2));
    float e0 = __expf(s0 - mx), e1 = __expf(s1 - mx), e2 = __expf(s2 - mx);
    float inv = 1.0f / (e0 + e1 + e2);
    int dd = lane * 2;
    float2 a0 = *(const float2*)&e[w][dd];
    float2 a1 = *(const float2*)&e[8 + w][dd];
    float2 a2 = *(const float2*)&e[16 + w][dd];
    float fx = (e0 * a0.x + e1 * a1.x + e2 * a2.x) * inv;
    float fy = (e0 * a0.y + e1 * a1.y + e2 * a2.y) * inv;
    *(float2*)&qf[w][dd] = make_float2(fx, fy);
    *(float2*)&resv[w][dd] = make_float2(fx, fy);
    resb[w][dd + 0] = f2bf(fx);
    resb[w][dd + 1] = f2bf(fy);
  }
  __syncthreads();

  // ---- residual VQ (MFMA distance GEMM), 3 codebooks; rows 8-15 pad ----
  for (int c = 0; c < C_; c++) {
    bf16x8 a[4];
#pragma unroll
    for (int ks = 0; ks < 4; ks++)
      a[ks] = *(const bf16x8*)&resb[ln][ks * 32 + q * 8];
    f32x4 acc[4];
#pragma unroll
    for (int tt = 0; tt < 4; tt++) acc[tt] = (f32x4){0.f, 0.f, 0.f, 0.f};
#pragma unroll
    for (int tt = 0; tt < 4; tt++) {
      const int n = w * 64 + tt * 16 + ln;
      const unsigned short* bp = cbb + ((size_t)c * K_ + n) * D_;
#pragma unroll
      for (int ks = 0; ks < 4; ks++) {
        bf16x8 b = *(const bf16x8*)(bp + ks * 32 + q * 8);
        acc[tt] = __builtin_amdgcn_mfma_f32_16x16x32_bf16(a[ks], b, acc[tt], 0, 0, 0);
      }
    }
    float bd[4]; int bk[4];
#pragma unroll
    for (int reg = 0; reg < 4; reg++) { bd[reg] = 3.4e38f; bk[reg] = 0x7fffffff; }
#pragma unroll
    for (int tt = 0; tt < 4; tt++) {
      const int col = w * 64 + tt * 16 + ln;
      const float n2 = cbn2[c * K_ + col];
#pragma unroll
      for (int reg = 0; reg < 4; reg++) {
        float dist = n2 - 2.0f * acc[tt][reg];
        if (dist < bd[reg] || (dist == bd[reg] && col < bk[reg])) { bd[reg] = dist; bk[reg] = col; }
      }
    }
#pragma unroll
    for (int reg = 0; reg < 4; reg++) {
#pragma unroll
      for (int off = 8; off > 0; off >>= 1) {
        float d1 = __shfl_down(bd[reg], off, 16);
        int k1 = __shfl_down(bk[reg], off, 16);
        if (d1 < bd[reg] || (d1 == bd[reg] && k1 < bk[reg])) { bd[reg] = d1; bk[reg] = k1; }
      }
      if (ln == 0) { candd[w][q * 4 + reg] = bd[reg]; candk[w][q * 4 + reg] = bk[reg]; }
    }
    __syncthreads();
    // all threads of wave w reduce the 8 wave-candidates for row w (LDS broadcast)
    float d0 = candd[0][w]; int k0c = candk[0][w];
#pragma unroll
    for (int ww = 1; ww < 8; ww++) {
      float d1 = candd[ww][w]; int k1 = candk[ww][w];
      if (d1 < d0 || (d1 == d0 && k1 < k0c)) { d0 = d1; k0c = k1; }
    }
    // update row w (wave-local)
    {
      int dd = lane * 2;
      float2 qv = *(const float2*)(cb + ((size_t)c * K_ + k0c) * D_ + dd);
      float2 rv = *(float2*)&resv[w][dd];
      rv.x -= qv.x; rv.y -= qv.y;
      *(float2*)&resv[w][dd] = rv;
      resb[w][dd + 0] = f2bf(rv.x);
      resb[w][dd + 1] = f2bf(rv.y);
    }
    if (c < C_ - 1) __syncthreads();   // next c's MFMA reads resb cross-wave
  }

  // ---- z1 = normalize(fused - res): wave-local, no barrier needed ----
  {
    int dd = lane * 2;
    float2 f = *(float2*)&qf[w][dd];
    float2 rv = *(float2*)&resv[w][dd];
    float zx0 = f.x - rv.x, zy0 = f.y - rv.y;
    float n2 = waveXorSum(zx0 * zx0 + zy0 * zy0);
    float inv = 1.0f / fmaxf(sqrtf(n2), EPS_);
    float zx = zx0 * inv, zy = zy0 * inv;
    zb[(size_t)(b0 + w) * D_ + dd + 0] = f2bf(zx);
    zb[(size_t)(b0 + w) * D_ + dd + 1] = f2bf(zy);
    qf[w][dd] = zx; qf[w][dd + 1] = zy;   // keep z1 f32 for pos
  }
  __syncthreads();

  // ---- z2 = normalize(emb) + pos = z1.z2: 8 waves x 3 rows ----
#pragma unroll
  for (int rr = 0; rr < 3; rr++) {
    int r = w * 3 + rr;                   // 0..23
    int s = r >> 3, bi = r & 7;
    int dd = lane * 2;
    float2 v = *(const float2*)&e[r][dd];
    float n2 = waveXorSum(v.x * v.x + v.y * v.y);
    float inv = 1.0f / fmaxf(sqrtf(n2), EPS_);
    float zx = v.x * inv, zy = v.y * inv;
    size_t gb = (size_t)(1 + s) * B_ + b0 + bi;
    zb[gb * D_ + dd + 0] = f2bf(zx);
    zb[gb * D_ + dd + 1] = f2bf(zy);
    float2 a1 = *(const float2*)&qf[bi][dd];
    float dsum = waveXorSum(a1.x * zx + a1.y * zy);
    if (lane == 0) pos[s * B_ + b0 + bi] = dsum;
  }
}

// ---------------- contrastive exp-rowsums: LDS-staged B tiles ----------------
__global__ __launch_bounds__(256) void contrast_mfma_kernel(
    const unsigned short* __restrict__ zb, float* __restrict__ rsP) {
  const int jc = blockIdx.x, ib = blockIdx.y, m = blockIdx.z;
  const int t = threadIdx.x;
  const int w = t >> 6, lane = t & 63;
  const int ln = lane & 15, q = lane >> 4;
  const int i0 = ib * 128 + w * 32;
  const unsigned short* Za = zb;
  const unsigned short* Zm = zb + (size_t)m * B_ * D_;

  __shared__ unsigned short Zsm[64 * 136];

  bf16x8 a[2][4];
#pragma unroll
  for (int si = 0; si < 2; si++)
#pragma unroll
    for (int ks = 0; ks < 4; ks++)
      a[si][ks] = *(const bf16x8*)(Za + (size_t)(i0 + si * 16 + ln) * D_ + ks * 32 + q * 8);

  const unsigned short* tb = Zm + (size_t)(jc * 1024) * D_;
  bf16x8 rz[4];
#pragma unroll
  for (int p = 0; p < 4; p++)
    rz[p] = *(const bf16x8*)(tb + t * 8 + p * 2048);

  float e[2][4] = {};
  for (int jt = 0; jt < 16; jt++) {
#pragma unroll
    for (int p = 0; p < 4; p++) {
      int c = t + p * 256;
      *(bf16x8*)&Zsm[(c >> 4) * 136 + (c & 15) * 8] = rz[p];
    }
    __syncthreads();
    if (jt + 1 < 16) {
      const unsigned short* tn = Zm + (size_t)(jc * 1024 + (jt + 1) * 64) * D_;
#pragma unroll
      for (int p = 0; p < 4; p++)
        rz[p] = *(const bf16x8*)(tn + t * 8 + p * 2048);
    }
    f32x4 acc[2][4];
#pragma unroll
    for (int si = 0; si < 2; si++)
#pragma unroll
      for (int tj = 0; tj < 4; tj++) acc[si][tj] = (f32x4){0.f, 0.f, 0.f, 0.f};
#pragma unroll
    for (int tj = 0; tj < 4; tj++) {
      bf16x8 b[4];
#pragma unroll
      for (int ks = 0; ks < 4; ks++)
        b[ks] = *(const bf16x8*)&Zsm[(tj * 16 + ln) * 136 + ks * 32 + q * 8];
#pragma unroll
      for (int ks = 0; ks < 4; ks++) {
        acc[0][tj] = __builtin_amdgcn_mfma_f32_16x16x32_bf16(a[0][ks], b[ks], acc[0][tj], 0, 0, 0);
        acc[1][tj] = __builtin_amdgcn_mfma_f32_16x16x32_bf16(a[1][ks], b[ks], acc[1][tj], 0, 0, 0);
      }
    }
#pragma unroll
    for (int si = 0; si < 2; si++)
#pragma unroll
      for (int reg = 0; reg < 4; reg++) {
        float s = 0.f;
#pragma unroll
        for (int tj = 0; tj < 4; tj++) s += __expf(acc[si][tj][reg] * INV_T);
        e[si][reg] += s;
      }
    __syncthreads();
  }
#pragma unroll
  for (int si = 0; si < 2; si++)
#pragma unroll
    for (int reg = 0; reg < 4; reg++) {
#pragma unroll
      for (int off = 8; off > 0; off >>= 1)
        e[si][reg] += __shfl_xor(e[si][reg], off, 16);
    }
  if (ln == 0) {
#pragma unroll
    for (int si = 0; si < 2; si++)
#pragma unroll
      for (int reg = 0; reg < 4; reg++)
        rsP[((size_t)m * 4 + jc) * B_ + i0 + si * 16 + q * 4 + reg] = e[si][reg];
  }
}

// ---------------- fused loss reduce + finalize (4 blocks) ----------------
__global__ __launch_bounds__(256) void final2_kernel(const float* __restrict__ rsP,
                                                     const float* __restrict__ pos,
                                                     const float* __restrict__ cbsumP,
                                                     float* __restrict__ out) {
  const int blk = blockIdx.x;
  const int t = threadIdx.x;
  __shared__ float red[4];
  if (blk == 0) {
    float acc = 0.0f;
    if (t < D_) {
#pragma unroll
      for (int m = 0; m < C_; m++) {
        float v = 0.0f;
#pragma unroll
        for (int b8 = 0; b8 < 8; b8++) v += cbsumP[(size_t)(m * 8 + b8) * D_ + t];
        acc += v * v;
      }
    }
    float v = waveReduceSum(acc);
    if ((t & 63) == 0) red[t >> 6] = v;
    __syncthreads();
    if (t == 0) {
      out[0] = (red[0] + red[1] + red[2] + red[3]) * (1.0f / (3.0f * 512.0f * 512.0f));
      out[1] = 0.0f;
    }
  } else {
    const int s = blk - 1;
    float acc = 0.0f;
    for (int it = 0; it < 16; it++) {
      const int i = it * 256 + t;
      float denom = -EXP10;
#pragma unroll
      for (int jc = 0; jc < 4; jc++) {
        denom += rsP[(size_t)jc * B_ + i];
        denom += rsP[((size_t)(1 + s) * 4 + jc) * B_ + i];
      }
      acc += logf(denom) - pos[s * B_ + i] * INV_T;
    }
    float v = waveReduceSum(acc);
    if ((t & 63) == 0) red[t >> 6] = v;
    __syncthreads();
    if (t == 0)
      out[2 + s] = (red[0] + red[1] + red[2] + red[3]) * (1.0f / 4096.0f);
  }
}

extern "C" void kernel_launch(void* const* d_in, const int* in_sizes, int n_in,
                              void* d_out, int out_size, void* d_ws, size_t ws_size,
                              hipStream_t stream) {
  const float* x    = (const float*)d_in[0];
  const float* w1   = (const float*)d_in[1];
  const float* b1   = (const float*)d_in[2];
  const float* w2   = (const float*)d_in[3];
  const float* b2   = (const float*)d_in[4];
  const float* w3   = (const float*)d_in[5];
  const float* b3   = (const float*)d_in[6];
  const float* w4   = (const float*)d_in[7];
  const float* b4   = (const float*)d_in[8];
  const float* qw1  = (const float*)d_in[9];
  const float* qb1  = (const float*)d_in[10];
  const float* qw2  = (const float*)d_in[11];
  const float* cb   = (const float*)d_in[12];
  float* out = (float*)d_out;
  char* base = (char*)d_ws;

  size_t o = 0;
  auto alloc = [&](size_t bytes) { size_t r = o; o += (bytes + 255) & ~(size_t)255; return r; };
  size_t o_xb   = alloc((size_t)S_ * B_ * DIN_ * 2);
  size_t o_wt1  = alloc((size_t)S_ * H1_ * DIN_ * 2);
  size_t o_wt2  = alloc((size_t)S_ * H2_ * H1_ * 2);
  size_t o_wt3  = alloc((size_t)S_ * H3_ * H2_ * 2);
  size_t o_w4t  = alloc((size_t)S_ * D_ * H3_ * 2);
  size_t o_h1b  = alloc((size_t)S_ * B_ * H1_ * 2);
  size_t o_h2b  = alloc((size_t)S_ * B_ * H2_ * 2);
  size_t o_h3b  = alloc((size_t)S_ * B_ * H3_ * 2);
  size_t o_zb   = alloc((size_t)4 * B_ * D_ * 2);
  size_t o_cbn2 = alloc((size_t)C_ * K_ * 4);
  size_t o_cbb  = alloc((size_t)C_ * K_ * D_ * 2);
  size_t o_rsP  = alloc((size_t)4 * 4 * B_ * 4);
  size_t o_cbsP = alloc((size_t)C_ * 8 * D_ * 4);
  size_t o_pos  = alloc((size_t)S_ * B_ * 4);
  size_t o_q1t  = alloc((size_t)D_ * D_ * 2);
  (void)ws_size; (void)in_sizes; (void)n_in; (void)out_size;

  unsigned short* xb  = (unsigned short*)(base + o_xb);
  unsigned short* wt1 = (unsigned short*)(base + o_wt1);
  unsigned short* wt2 = (unsigned short*)(base + o_wt2);
  unsigned short* wt3 = (unsigned short*)(base + o_wt3);
  unsigned short* w4tb= (unsigned short*)(base + o_w4t);
  unsigned short* h1b = (unsigned short*)(base + o_h1b);
  unsigned short* h2b = (unsigned short*)(base + o_h2b);
  unsigned short* h3b = (unsigned short*)(base + o_h3b);
  unsigned short* zb = (unsigned short*)(base + o_zb);
  float* cbn2  = (float*)(base + o_cbn2);
  unsigned short* cbb = (unsigned short*)(base + o_cbb);
  float* rsP   = (float*)(base + o_rsP);
  float* cbsumP= (float*)(base + o_cbsP);
  float* pos   = (float*)(base + o_pos);
  unsigned short* qw1tb = (unsigned short*)(base + o_q1t);

  // fused prep: x->bf16 + weight transposes + codebook norms + qw1^T (one launch)
  const int prep_blocks = (S_ * B_ * DIN_) / 1024 + 1536 + 576 + 288 + 96 + C_ * 8 + 16;
  prep_kernel<<<dim3(prep_blocks), 256, 0, stream>>>(x, xb, w1, wt1, w2, wt2, w3, wt3, w4, w4tb,
                                                     cb, cbn2, cbsumP, cbb, qw1, qw1tb);

  // encoder MLP layers 1-3 via LDS-staged MFMA (BK=64, async B staging)
  const int Mtot = S_ * B_;
  gemm_lds_kernel<<<dim3(H1_ / 128, Mtot / 64), 256, 0, stream>>>(xb, wt1, b1, h1b, DIN_, H1_, 1, 0);
  gemm_lds_kernel<<<dim3(H2_ / 128, Mtot / 64), 256, 0, stream>>>(h1b, wt2, b2, h2b, H1_, H2_, 1, 0);
  gemm_lds_kernel<<<dim3(H3_ / 128, Mtot / 64), 256, 0, stream>>>(h2b, wt3, b3, h3b, H2_, H3_, 1, 0);

  // mega-fused: layer-4 GEMM -> MFMA score -> softmax+fuse -> VQ -> normalize+pos
  // 8 rows/block -> 512 blocks -> 2 blocks/CU for latency overlap
  l4vq_kernel<<<dim3(B_ / 8), 512, 0, stream>>>(h3b, w4tb, b4, qw1tb, qb1, qw2,
                                                cb, cbb, cbn2, zb, pos);

  // contrastive rowsum partials
  contrast_mfma_kernel<<<dim3(4, 32, 4), 256, 0, stream>>>(zb, rsP);

  // fused loss reduce + finalize
  final2_kernel<<<dim3(4), 256, 0, stream>>>(rsP, pos, cbsumP, out);
}

// Round 7
// 243.387 us; speedup vs baseline: 1.0073x; 1.0073x over previous
//
#include <hip/hip_runtime.h>
#include <hip/hip_bf16.h>

// Problem constants
#define S_   3
#define B_   4096
#define DIN_ 1024
#define H1_  512
#define H2_  384
#define H3_  256
#define D_   128
#define K_   512
#define C_   3
#define INV_T 10.0f          // 1/TEMP
#define EPS_  1e-12f
#define EXP10 22026.465794806718f   // exp(1/T), diag(refl) analytically

typedef float f32x4 __attribute__((ext_vector_type(4)));
typedef short bf16x8 __attribute__((ext_vector_type(8)));

__device__ __forceinline__ unsigned short f2bf(float f) {
  unsigned int u = __float_as_uint(f);
  u = (u + 0x7FFF + ((u >> 16) & 1)) >> 16;   // round-to-nearest-even
  return (unsigned short)u;
}

// async 16B-per-lane global -> LDS (wave-uniform base + lane*16 on both sides)
__device__ __forceinline__ void gl2lds16(const unsigned short* g, unsigned short* l) {
  __builtin_amdgcn_global_load_lds(
      (const __attribute__((address_space(1))) void*)g,
      (__attribute__((address_space(3))) void*)l, 16, 0, 0);
}

// ---------------- reduction helpers ----------------
__device__ __forceinline__ float waveReduceSum(float v) {
#pragma unroll
  for (int off = 32; off > 0; off >>= 1) v += __shfl_down(v, off, 64);
  return v;
}

__device__ __forceinline__ float waveXorSum(float v) {
#pragma unroll
  for (int off = 32; off > 0; off >>= 1) v += __shfl_xor(v, off, 64);
  return v;
}

// ------- fused prep: x cvt + weight transposes (w4 plain) + cb norms + qw1^T -----
__global__ __launch_bounds__(256) void prep_kernel(
    const float* __restrict__ x, unsigned short* __restrict__ xb,
    const float* __restrict__ w1, unsigned short* __restrict__ wt1,
    const float* __restrict__ w2, unsigned short* __restrict__ wt2,
    const float* __restrict__ w3, unsigned short* __restrict__ wt3,
    const float* __restrict__ w4, unsigned short* __restrict__ w4tb,
    const float* __restrict__ cb, float* __restrict__ cbn2,
    float* __restrict__ cbsumP, unsigned short* __restrict__ cbb,
    const float* __restrict__ qw1, unsigned short* __restrict__ qw1tb) {
  __shared__ float tt[32][33];
  __shared__ float invn[64];
  const int t = threadIdx.x;
  int blk = blockIdx.x;
  const int NCVT = (S_ * B_ * DIN_) / 1024;   // 12288
  if (blk < NCVT) {
    int i = (blk * 256 + t) * 4;
    float4 v = *(const float4*)(x + i);
    xb[i + 0] = f2bf(v.x); xb[i + 1] = f2bf(v.y);
    xb[i + 2] = f2bf(v.z); xb[i + 3] = f2bf(v.w);
    return;
  }
  blk -= NCVT;
  const int NT = 1536 + 576 + 288 + 96;       // 2496 transpose blocks
  if (blk >= NT) {
    int cblk = blk - NT;
    if (cblk < 24) {
      // ---- codebook norms + bf16 convert + column-sum partials ----
      const int m = cblk >> 3;
      const int k0 = (cblk & 7) * 64;
      const int w = t >> 6, lane = t & 63;
      for (int r = w * 16; r < w * 16 + 16; r++) {
        int k = k0 + r;
        float2 v = *(const float2*)(cb + ((size_t)m * K_ + k) * D_ + lane * 2);
        unsigned short* crow = cbb + ((size_t)m * K_ + k) * D_;
        crow[lane * 2 + 0] = f2bf(v.x);
        crow[lane * 2 + 1] = f2bf(v.y);
        float n2 = waveXorSum(v.x * v.x + v.y * v.y);
        if (lane == 0) {
          cbn2[m * K_ + k] = n2;
          invn[r] = 1.0f / fmaxf(sqrtf(n2), EPS_);
        }
      }
      __syncthreads();
      if (t < D_) {
        float acc = 0.0f;
        for (int r = 0; r < 64; r++)
          acc += cb[((size_t)m * K_ + k0 + r) * D_ + t] * invn[r];
        cbsumP[(size_t)cblk * D_ + t] = acc;
      }
      return;
    }
    // ---- qw1^T bf16 (d-major): 16 blocks of 32x32 ----
    cblk -= 24;                                // [0,16)
    const int kx = cblk & 3, ny = cblk >> 2;
    const int k0 = kx * 32, n0 = ny * 32;
    const int tx = t & 31, ty = t >> 5;
#pragma unroll
    for (int i = 0; i < 4; i++)
      tt[ty + 8 * i][tx] = qw1[(size_t)(k0 + ty + 8 * i) * D_ + n0 + tx];
    __syncthreads();
#pragma unroll
    for (int i = 0; i < 4; i++)
      qw1tb[(size_t)(n0 + ty + 8 * i) * D_ + k0 + tx] = f2bf(tt[tx][ty + 8 * i]);
    return;
  }
  const float* W; unsigned short* Wt; int K, N; int plain = 0;
  if (blk < 1536) { W = w1; Wt = wt1; K = DIN_; N = H1_; }
  else {
    blk -= 1536;
    if (blk < 576) { W = w2; Wt = wt2; K = H1_; N = H2_; }
    else {
      blk -= 576;
      if (blk < 288) { W = w3; Wt = wt3; K = H2_; N = H3_; }
      else { blk -= 288; W = w4; Wt = w4tb; K = H3_; N = D_; plain = 1; }
    }
  }
  const int kx_n = K / 32, ny_n = N / 32;
  const int kx = blk % kx_n;
  const int ny = (blk / kx_n) % ny_n;
  const int s  = blk / (kx_n * ny_n);
  const int k0 = kx * 32, n0 = ny * 32;
  const int tx = t & 31, ty = t >> 5;        // 32 x 8
  const float* Ws = W + (size_t)s * K * N;
  const int nb = N >> 7, kb = K >> 6;
#pragma unroll
  for (int i = 0; i < 4; i++)
    tt[ty + 8 * i][tx] = Ws[(size_t)(k0 + ty + 8 * i) * N + n0 + tx];
  __syncthreads();
  const int k = k0 + tx;
  if (plain) {
    // w4^T: [s][n][k] plain bf16 for direct fragment loads
#pragma unroll
    for (int i = 0; i < 4; i++) {
      int n = n0 + ty + 8 * i;
      Wt[((size_t)(s * D_ + n)) * H3_ + k] = f2bf(tt[tx][ty + 8 * i]);
    }
  } else {
    const int kt = k >> 6, ksl = (k >> 5) & 1;
#pragma unroll
    for (int i = 0; i < 4; i++) {
      int n = n0 + ty + 8 * i;
      size_t dst = ((size_t)(s * nb + (n >> 7)) * kb + kt) * 8192 +
                   (size_t)ksl * 4096 + (size_t)(n & 127) * 32 + (k & 31);
      Wt[dst] = f2bf(tt[tx][ty + 8 * i]);
    }
  }
}

// ---------------- LDS-staged MFMA GEMM, BK=64, async B via global_load_lds -------
__global__ __launch_bounds__(256) void gemm_lds_kernel(
    const unsigned short* __restrict__ A, const unsigned short* __restrict__ Wsw,
    const float* __restrict__ bias, void* __restrict__ Y,
    int K, int N, int relu, int out_f32) {
  const int t = threadIdx.x;
  const int lane = t & 63;
  const int w = t >> 6;
  const int ln = lane & 15, q = lane >> 4;
  const int wm = w >> 1, wn = w & 1;
  const int n0 = blockIdx.x * 128;
  const int mblk = blockIdx.y;
  const int s = mblk >> 6;                  // 4096/64 = 64 m-blocks per source
  const int m0 = mblk * 64;
  const int nb = N >> 7, kb = K >> 6;

  const unsigned short* Ag = A + (size_t)m0 * K;
  const unsigned short* Bt = Wsw + ((size_t)(s * nb + blockIdx.x) * kb) * 8192;
  const float* bs = bias + (size_t)s * N;

  __shared__ unsigned short Asm[2 * 64 * 32];     // 8 KB (two 32-k halves)
  __shared__ unsigned short Bsm[2 * 8192];        // 32 KB double buffer

  const int arow0 = t >> 3, ak8 = t & 7;
  const int aL0 = (ak8 >> 2) * 2048 + arow0 * 32 + (ak8 & 3) * 8;
  const size_t gA0 = (size_t)arow0 * K + ak8 * 8;

  // preload A regs (tile 0) + issue async B tile 0
  bf16x8 ra0 = *(const bf16x8*)(Ag + gA0);
  bf16x8 ra1 = *(const bf16x8*)(Ag + gA0 + (size_t)32 * K);
#pragma unroll
  for (int p = 0; p < 4; p++)
    gl2lds16(Bt + (size_t)(p * 256 + t) * 8, &Bsm[(size_t)(p * 256 + t) * 8]);

  f32x4 acc[2][4];
#pragma unroll
  for (int i = 0; i < 2; i++)
#pragma unroll
    for (int j = 0; j < 4; j++) acc[i][j] = (f32x4){0.f, 0.f, 0.f, 0.f};

  for (int kt = 0; kt < kb; kt++) {
    *(bf16x8*)&Asm[aL0] = ra0;
    *(bf16x8*)&Asm[aL0 + 1024] = ra1;
    __syncthreads();                       // drains vmcnt: B tile kt complete
    const unsigned short* Bcur = &Bsm[(kt & 1) * 8192];
    if (kt + 1 < kb) {
      const unsigned short* Bn = Bt + (size_t)(kt + 1) * 8192;
      unsigned short* Bd = &Bsm[((kt + 1) & 1) * 8192];
#pragma unroll
      for (int p = 0; p < 4; p++)
        gl2lds16(Bn + (size_t)(p * 256 + t) * 8, Bd + (size_t)(p * 256 + t) * 8);
      const size_t g = gA0 + (size_t)(kt + 1) * 64;
      ra0 = *(const bf16x8*)(Ag + g);
      ra1 = *(const bf16x8*)(Ag + g + (size_t)32 * K);
    }
    bf16x8 af[2][2], bf[4][2];
#pragma unroll
    for (int ti = 0; ti < 2; ti++)
#pragma unroll
      for (int ksl = 0; ksl < 2; ksl++)
        af[ti][ksl] = *(const bf16x8*)&Asm[ksl * 2048 + (wm * 32 + ti * 16 + ln) * 32 + q * 8];
#pragma unroll
    for (int tj = 0; tj < 4; tj++)
#pragma unroll
      for (int ksl = 0; ksl < 2; ksl++)
        bf[tj][ksl] = *(const bf16x8*)&Bcur[ksl * 4096 + (wn * 64 + tj * 16 + ln) * 32 + q * 8];
#pragma unroll
    for (int ksl = 0; ksl < 2; ksl++)
#pragma unroll
      for (int ti = 0; ti < 2; ti++)
#pragma unroll
        for (int tj = 0; tj < 4; tj++)
          acc[ti][tj] = __builtin_amdgcn_mfma_f32_16x16x32_bf16(af[ti][ksl], bf[tj][ksl], acc[ti][tj], 0, 0, 0);
    __syncthreads();
  }

#pragma unroll
  for (int ti = 0; ti < 2; ti++)
#pragma unroll
    for (int tj = 0; tj < 4; tj++) {
      const int cc = n0 + wn * 64 + tj * 16 + ln;
      const float bv = bs[cc];
#pragma unroll
      for (int reg = 0; reg < 4; reg++) {
        const int r = m0 + wm * 32 + ti * 16 + q * 4 + reg;
        float v = acc[ti][tj][reg] + bv;
        if (relu) v = fmaxf(v, 0.0f);
        if (out_f32) ((float*)Y)[(size_t)r * N + cc] = v;
        else ((unsigned short*)Y)[(size_t)r * N + cc] = f2bf(v);
      }
    }
}

// -------- mega-fused: layer-4 GEMM -> MFMA score -> softmax+fuse -> VQ -> norm ----
// 16 batch rows per block, 256 blocks, 512 threads (8 waves). Layer-4 A-fragments
// are read directly from global (L2-hot, same 24 KB tile for all 8 waves) -> no
// h3 LDS staging -> ~59.6 KB LDS -> 2 blocks/CU for latency overlap.
__global__ __launch_bounds__(512) void l4vq_kernel(
    const unsigned short* __restrict__ h3b, const unsigned short* __restrict__ w4tb,
    const float* __restrict__ b4, const unsigned short* __restrict__ qw1tb,
    const float* __restrict__ qb1, const float* __restrict__ qw2,
    const float* __restrict__ cb, const unsigned short* __restrict__ cbb,
    const float* __restrict__ cbn2,
    unsigned short* __restrict__ zb, float* __restrict__ pos) {
  const int b0 = blockIdx.x * 16;
  const int t = threadIdx.x;
  const int w = t >> 6, lane = t & 63;
  const int ln = lane & 15, q = lane >> 4;

  __shared__ float e[48][D_];             // emb rows f32, r = s*16+bi    (24 KB)
  __shared__ unsigned short ebb[48][136]; // emb rows bf16 (padded)       (12.75 KB)
  __shared__ float qf[16][D_];            // fused -> qsum -> z1          (8 KB)
  __shared__ float resv[16][D_];          // residual f32                 (8 KB)
  __shared__ unsigned short resb[16][136];// residual bf16 (padded)       (4.25 KB)
  __shared__ float red2[8][48];
  __shared__ float sc[48];
  __shared__ float candd[8][16];
  __shared__ int candk[8][16];
  __shared__ int bestk[16];

  // B fragments of qw1^T for this wave's 16 score-cols (global, L2-hot)
  bf16x8 bq[4];
  {
    const unsigned short* qp = qw1tb + (size_t)(w * 16 + ln) * D_;
#pragma unroll
    for (int ks = 0; ks < 4; ks++)
      bq[ks] = *(const bf16x8*)(qp + ks * 32 + q * 8);
  }

  // ---- layer-4 GEMM: emb[s][bi][col] for col = w*16+ln, bi = q*4+reg ----
  // A-fragments straight from global h3b (each wave reads the same 48x256 tile;
  // L2-served). No staging barrier needed before this phase.
  {
    const int col = w * 16 + ln;
#pragma unroll
    for (int s = 0; s < 3; s++) {
      f32x4 oacc = (f32x4){0.f, 0.f, 0.f, 0.f};
      const unsigned short* wp = w4tb + ((size_t)(s * D_ + col)) * H3_;
      const unsigned short* ap = h3b + ((size_t)(s * B_ + b0 + ln)) * H3_;
#pragma unroll
      for (int ks = 0; ks < 8; ks++) {
        bf16x8 bfrag = *(const bf16x8*)(wp + ks * 32 + q * 8);
        bf16x8 afrag = *(const bf16x8*)(ap + ks * 32 + q * 8);
        oacc = __builtin_amdgcn_mfma_f32_16x16x32_bf16(afrag, bfrag, oacc, 0, 0, 0);
      }
      const float bv = b4[s * D_ + col];
#pragma unroll
      for (int reg = 0; reg < 4; reg++) {
        int r = s * 16 + q * 4 + reg;
        float v = oacc[reg] + bv;
        e[r][col] = v;
        ebb[r][col] = f2bf(v);
      }
    }
  }
  __syncthreads();

  // ---- attention scores via MFMA: h[r][col] for col = w*16+ln ----
  {
    f32x4 sacc[3];
#pragma unroll
    for (int rt = 0; rt < 3; rt++) sacc[rt] = (f32x4){0.f, 0.f, 0.f, 0.f};
#pragma unroll
    for (int ks = 0; ks < 4; ks++) {
#pragma unroll
      for (int rt = 0; rt < 3; rt++) {
        bf16x8 a = *(const bf16x8*)&ebb[rt * 16 + ln][ks * 32 + q * 8];
        sacc[rt] = __builtin_amdgcn_mfma_f32_16x16x32_bf16(a, bq[ks], sacc[rt], 0, 0, 0);
      }
    }
    const int col = w * 16 + ln;
    const float qb = qb1[col], q2v = qw2[col];
#pragma unroll
    for (int rt = 0; rt < 3; rt++)
#pragma unroll
      for (int reg = 0; reg < 4; reg++) {
        float v = tanhf(sacc[rt][reg] + qb) * q2v;
#pragma unroll
        for (int off = 8; off > 0; off >>= 1) v += __shfl_xor(v, off, 16);
        if (ln == 0) red2[w][rt * 16 + q * 4 + reg] = v;
      }
  }
  __syncthreads();
  if (t < 48) {
    float s = 0.f;
#pragma unroll
    for (int ww = 0; ww < 8; ww++) s += red2[ww][t];
    sc[t] = s;                                 // sc[r], r = s*16+bi
  }
  __syncthreads();

  // ---- softmax over sources + fuse -> residual buffers ----
#pragma unroll
  for (int p = 0; p < 4; p++) {
    int idx = p * 512 + t;
    int bi = idx >> 7, dd = idx & 127;
    float s0 = sc[bi], s1 = sc[16 + bi], s2 = sc[32 + bi];
    float mx = fmaxf(s0, fmaxf(s1, s2));
    float e0 = __expf(s0 - mx), e1 = __expf(s1 - mx), e2 = __expf(s2 - mx);
    float inv = 1.0f / (e0 + e1 + e2);
    float fv = (e0 * e[bi][dd] + e1 * e[16 + bi][dd] + e2 * e[32 + bi][dd]) * inv;
    qf[bi][dd] = fv;
    resv[bi][dd] = fv;
    resb[bi][dd] = f2bf(fv);
  }
  __syncthreads();

  // ---- residual VQ (MFMA distance GEMM), 3 codebooks ----
  for (int c = 0; c < C_; c++) {
    bf16x8 a[4];
#pragma unroll
    for (int ks = 0; ks < 4; ks++)
      a[ks] = *(const bf16x8*)&resb[ln][ks * 32 + q * 8];
    f32x4 acc[4];
#pragma unroll
    for (int tt = 0; tt < 4; tt++) acc[tt] = (f32x4){0.f, 0.f, 0.f, 0.f};
#pragma unroll
    for (int tt = 0; tt < 4; tt++) {
      const int n = w * 64 + tt * 16 + ln;
      const unsigned short* bp = cbb + ((size_t)c * K_ + n) * D_;
#pragma unroll
      for (int ks = 0; ks < 4; ks++) {
        bf16x8 b = *(const bf16x8*)(bp + ks * 32 + q * 8);
        acc[tt] = __builtin_amdgcn_mfma_f32_16x16x32_bf16(a[ks], b, acc[tt], 0, 0, 0);
      }
    }
    float bd[4]; int bk[4];
#pragma unroll
    for (int reg = 0; reg < 4; reg++) { bd[reg] = 3.4e38f; bk[reg] = 0x7fffffff; }
#pragma unroll
    for (int tt = 0; tt < 4; tt++) {
      const int col = w * 64 + tt * 16 + ln;
      const float n2 = cbn2[c * K_ + col];
#pragma unroll
      for (int reg = 0; reg < 4; reg++) {
        float dist = n2 - 2.0f * acc[tt][reg];
        if (dist < bd[reg] || (dist == bd[reg] && col < bk[reg])) { bd[reg] = dist; bk[reg] = col; }
      }
    }
#pragma unroll
    for (int reg = 0; reg < 4; reg++) {
#pragma unroll
      for (int off = 8; off > 0; off >>= 1) {
        float d1 = __shfl_down(bd[reg], off, 16);
        int k1 = __shfl_down(bk[reg], off, 16);
        if (d1 < bd[reg] || (d1 == bd[reg] && k1 < bk[reg])) { bd[reg] = d1; bk[reg] = k1; }
      }
      if (ln == 0) { candd[w][q * 4 + reg] = bd[reg]; candk[w][q * 4 + reg] = bk[reg]; }
    }
    __syncthreads();
    if (w == 0) {
      int row = lane >> 2, g = lane & 3;
      float d0 = candd[2 * g][row]; int k0 = candk[2 * g][row];
      float d1 = candd[2 * g + 1][row]; int k1 = candk[2 * g + 1][row];
      if (d1 < d0 || (d1 == d0 && k1 < k0)) { d0 = d1; k0 = k1; }
#pragma unroll
      for (int off = 2; off > 0; off >>= 1) {
        float dn = __shfl_down(d0, off, 4);
        int kn = __shfl_down(k0, off, 4);
        if (dn < d0 || (dn == d0 && kn < k0)) { d0 = dn; k0 = kn; }
      }
      if (g == 0) bestk[row] = k0;
    }
    __syncthreads();
    {
      int idx = t * 4;
      int r = idx >> 7, dd = idx & 127;
      const float4 qv = *(const float4*)(cb + ((size_t)c * K_ + bestk[r]) * D_ + dd);
      float4 rv = *(float4*)&resv[r][dd];
      rv.x -= qv.x; rv.y -= qv.y; rv.z -= qv.z; rv.w -= qv.w;
      *(float4*)&resv[r][dd] = rv;
      resb[r][dd + 0] = f2bf(rv.x); resb[r][dd + 1] = f2bf(rv.y);
      resb[r][dd + 2] = f2bf(rv.z); resb[r][dd + 3] = f2bf(rv.w);
    }
    __syncthreads();
  }

  // ---- qsum = fused - res (in LDS) ----
  {
    int idx = t * 4;
    int r = idx >> 7, dd = idx & 127;
    float4 f = *(float4*)&qf[r][dd];
    float4 rv = *(float4*)&resv[r][dd];
    f.x -= rv.x; f.y -= rv.y; f.z -= rv.z; f.w -= rv.w;
    *(float4*)&qf[r][dd] = f;
  }
  __syncthreads();

  // ---- z1 = normalize(qsum): 8 waves x 2 rows ----
#pragma unroll
  for (int rr = 0; rr < 2; rr++) {
    int r = w * 2 + rr;
    float2 v = *(const float2*)&qf[r][lane * 2];
    float n2 = waveXorSum(v.x * v.x + v.y * v.y);
    float inv = 1.0f / fmaxf(sqrtf(n2), EPS_);
    float zx = v.x * inv, zy = v.y * inv;
    zb[(size_t)(b0 + r) * D_ + lane * 2 + 0] = f2bf(zx);
    zb[(size_t)(b0 + r) * D_ + lane * 2 + 1] = f2bf(zy);
    qf[r][lane * 2] = zx; qf[r][lane * 2 + 1] = zy;   // keep z1 f32 for pos
  }
  __syncthreads();

  // ---- z2 = normalize(emb) + pos = z1.z2: 8 waves x 6 rows ----
#pragma unroll
  for (int rr = 0; rr < 6; rr++) {
    int r = w * 6 + rr;
    int s = r >> 4, bi = r & 15;
    float2 v = *(const float2*)&e[r][lane * 2];
    float n2 = waveXorSum(v.x * v.x + v.y * v.y);
    float inv = 1.0f / fmaxf(sqrtf(n2), EPS_);
    float zx = v.x * inv, zy = v.y * inv;
    size_t gb = (size_t)(1 + s) * B_ + b0 + bi;
    zb[gb * D_ + lane * 2 + 0] = f2bf(zx);
    zb[gb * D_ + lane * 2 + 1] = f2bf(zy);
    float2 a1 = *(const float2*)&qf[bi][lane * 2];
    float dsum = waveXorSum(a1.x * zx + a1.y * zy);
    if (lane == 0) pos[s * B_ + b0 + bi] = dsum;
  }
}

// ---------------- contrastive exp-rowsums: LDS-staged B tiles ----------------
__global__ __launch_bounds__(256) void contrast_mfma_kernel(
    const unsigned short* __restrict__ zb, float* __restrict__ rsP) {
  const int jc = blockIdx.x, ib = blockIdx.y, m = blockIdx.z;
  const int t = threadIdx.x;
  const int w = t >> 6, lane = t & 63;
  const int ln = lane & 15, q = lane >> 4;
  const int i0 = ib * 128 + w * 32;
  const unsigned short* Za = zb;
  const unsigned short* Zm = zb + (size_t)m * B_ * D_;

  __shared__ unsigned short Zsm[64 * 136];

  bf16x8 a[2][4];
#pragma unroll
  for (int si = 0; si < 2; si++)
#pragma unroll
    for (int ks = 0; ks < 4; ks++)
      a[si][ks] = *(const bf16x8*)(Za + (size_t)(i0 + si * 16 + ln) * D_ + ks * 32 + q * 8);

  const unsigned short* tb = Zm + (size_t)(jc * 1024) * D_;
  bf16x8 rz[4];
#pragma unroll
  for (int p = 0; p < 4; p++)
    rz[p] = *(const bf16x8*)(tb + t * 8 + p * 2048);

  float e[2][4] = {};
  for (int jt = 0; jt < 16; jt++) {
#pragma unroll
    for (int p = 0; p < 4; p++) {
      int c = t + p * 256;
      *(bf16x8*)&Zsm[(c >> 4) * 136 + (c & 15) * 8] = rz[p];
    }
    __syncthreads();
    if (jt + 1 < 16) {
      const unsigned short* tn = Zm + (size_t)(jc * 1024 + (jt + 1) * 64) * D_;
#pragma unroll
      for (int p = 0; p < 4; p++)
        rz[p] = *(const bf16x8*)(tn + t * 8 + p * 2048);
    }
    f32x4 acc[2][4];
#pragma unroll
    for (int si = 0; si < 2; si++)
#pragma unroll
      for (int tj = 0; tj < 4; tj++) acc[si][tj] = (f32x4){0.f, 0.f, 0.f, 0.f};
#pragma unroll
    for (int tj = 0; tj < 4; tj++) {
      bf16x8 b[4];
#pragma unroll
      for (int ks = 0; ks < 4; ks++)
        b[ks] = *(const bf16x8*)&Zsm[(tj * 16 + ln) * 136 + ks * 32 + q * 8];
#pragma unroll
      for (int ks = 0; ks < 4; ks++) {
        acc[0][tj] = __builtin_amdgcn_mfma_f32_16x16x32_bf16(a[0][ks], b[ks], acc[0][tj], 0, 0, 0);
        acc[1][tj] = __builtin_amdgcn_mfma_f32_16x16x32_bf16(a[1][ks], b[ks], acc[1][tj], 0, 0, 0);
      }
    }
#pragma unroll
    for (int si = 0; si < 2; si++)
#pragma unroll
      for (int reg = 0; reg < 4; reg++) {
        float s = 0.f;
#pragma unroll
        for (int tj = 0; tj < 4; tj++) s += __expf(acc[si][tj][reg] * INV_T);
        e[si][reg] += s;
      }
    __syncthreads();
  }
#pragma unroll
  for (int si = 0; si < 2; si++)
#pragma unroll
    for (int reg = 0; reg < 4; reg++) {
#pragma unroll
      for (int off = 8; off > 0; off >>= 1)
        e[si][reg] += __shfl_xor(e[si][reg], off, 16);
    }
  if (ln == 0) {
#pragma unroll
    for (int si = 0; si < 2; si++)
#pragma unroll
      for (int reg = 0; reg < 4; reg++)
        rsP[((size_t)m * 4 + jc) * B_ + i0 + si * 16 + q * 4 + reg] = e[si][reg];
  }
}

// ---------------- fused loss reduce + finalize (4 blocks) ----------------
__global__ __launch_bounds__(256) void final2_kernel(const float* __restrict__ rsP,
                                                     const float* __restrict__ pos,
                                                     const float* __restrict__ cbsumP,
                                                     float* __restrict__ out) {
  const int blk = blockIdx.x;
  const int t = threadIdx.x;
  __shared__ float red[4];
  if (blk == 0) {
    float acc = 0.0f;
    if (t < D_) {
#pragma unroll
      for (int m = 0; m < C_; m++) {
        float v = 0.0f;
#pragma unroll
        for (int b8 = 0; b8 < 8; b8++) v += cbsumP[(size_t)(m * 8 + b8) * D_ + t];
        acc += v * v;
      }
    }
    float v = waveReduceSum(acc);
    if ((t & 63) == 0) red[t >> 6] = v;
    __syncthreads();
    if (t == 0) {
      out[0] = (red[0] + red[1] + red[2] + red[3]) * (1.0f / (3.0f * 512.0f * 512.0f));
      out[1] = 0.0f;
    }
  } else {
    const int s = blk - 1;
    float acc = 0.0f;
    for (int it = 0; it < 16; it++) {
      const int i = it * 256 + t;
      float denom = -EXP10;
#pragma unroll
      for (int jc = 0; jc < 4; jc++) {
        denom += rsP[(size_t)jc * B_ + i];
        denom += rsP[((size_t)(1 + s) * 4 + jc) * B_ + i];
      }
      acc += logf(denom) - pos[s * B_ + i] * INV_T;
    }
    float v = waveReduceSum(acc);
    if ((t & 63) == 0) red[t >> 6] = v;
    __syncthreads();
    if (t == 0)
      out[2 + s] = (red[0] + red[1] + red[2] + red[3]) * (1.0f / 4096.0f);
  }
}

extern "C" void kernel_launch(void* const* d_in, const int* in_sizes, int n_in,
                              void* d_out, int out_size, void* d_ws, size_t ws_size,
                              hipStream_t stream) {
  const float* x    = (const float*)d_in[0];
  const float* w1   = (const float*)d_in[1];
  const float* b1   = (const float*)d_in[2];
  const float* w2   = (const float*)d_in[3];
  const float* b2   = (const float*)d_in[4];
  const float* w3   = (const float*)d_in[5];
  const float* b3   = (const float*)d_in[6];
  const float* w4   = (const float*)d_in[7];
  const float* b4   = (const float*)d_in[8];
  const float* qw1  = (const float*)d_in[9];
  const float* qb1  = (const float*)d_in[10];
  const float* qw2  = (const float*)d_in[11];
  const float* cb   = (const float*)d_in[12];
  float* out = (float*)d_out;
  char* base = (char*)d_ws;

  size_t o = 0;
  auto alloc = [&](size_t bytes) { size_t r = o; o += (bytes + 255) & ~(size_t)255; return r; };
  size_t o_xb   = alloc((size_t)S_ * B_ * DIN_ * 2);
  size_t o_wt1  = alloc((size_t)S_ * H1_ * DIN_ * 2);
  size_t o_wt2  = alloc((size_t)S_ * H2_ * H1_ * 2);
  size_t o_wt3  = alloc((size_t)S_ * H3_ * H2_ * 2);
  size_t o_w4t  = alloc((size_t)S_ * D_ * H3_ * 2);
  size_t o_h1b  = alloc((size_t)S_ * B_ * H1_ * 2);
  size_t o_h2b  = alloc((size_t)S_ * B_ * H2_ * 2);
  size_t o_h3b  = alloc((size_t)S_ * B_ * H3_ * 2);
  size_t o_zb   = alloc((size_t)4 * B_ * D_ * 2);
  size_t o_cbn2 = alloc((size_t)C_ * K_ * 4);
  size_t o_cbb  = alloc((size_t)C_ * K_ * D_ * 2);
  size_t o_rsP  = alloc((size_t)4 * 4 * B_ * 4);
  size_t o_cbsP = alloc((size_t)C_ * 8 * D_ * 4);
  size_t o_pos  = alloc((size_t)S_ * B_ * 4);
  size_t o_q1t  = alloc((size_t)D_ * D_ * 2);
  (void)ws_size; (void)in_sizes; (void)n_in; (void)out_size;

  unsigned short* xb  = (unsigned short*)(base + o_xb);
  unsigned short* wt1 = (unsigned short*)(base + o_wt1);
  unsigned short* wt2 = (unsigned short*)(base + o_wt2);
  unsigned short* wt3 = (unsigned short*)(base + o_wt3);
  unsigned short* w4tb= (unsigned short*)(base + o_w4t);
  unsigned short* h1b = (unsigned short*)(base + o_h1b);
  unsigned short* h2b = (unsigned short*)(base + o_h2b);
  unsigned short* h3b = (unsigned short*)(base + o_h3b);
  unsigned short* zb = (unsigned short*)(base + o_zb);
  float* cbn2  = (float*)(base + o_cbn2);
  unsigned short* cbb = (unsigned short*)(base + o_cbb);
  float* rsP   = (float*)(base + o_rsP);
  float* cbsumP= (float*)(base + o_cbsP);
  float* pos   = (float*)(base + o_pos);
  unsigned short* qw1tb = (unsigned short*)(base + o_q1t);

  // fused prep: x->bf16 + weight transposes + codebook norms + qw1^T (one launch)
  const int prep_blocks = (S_ * B_ * DIN_) / 1024 + 1536 + 576 + 288 + 96 + C_ * 8 + 16;
  prep_kernel<<<dim3(prep_blocks), 256, 0, stream>>>(x, xb, w1, wt1, w2, wt2, w3, wt3, w4, w4tb,
                                                     cb, cbn2, cbsumP, cbb, qw1, qw1tb);

  // encoder MLP layers 1-3 via LDS-staged MFMA (BK=64, async B staging)
  const int Mtot = S_ * B_;
  gemm_lds_kernel<<<dim3(H1_ / 128, Mtot / 64), 256, 0, stream>>>(xb, wt1, b1, h1b, DIN_, H1_, 1, 0);
  gemm_lds_kernel<<<dim3(H2_ / 128, Mtot / 64), 256, 0, stream>>>(h1b, wt2, b2, h2b, H1_, H2_, 1, 0);
  gemm_lds_kernel<<<dim3(H3_ / 128, Mtot / 64), 256, 0, stream>>>(h2b, wt3, b3, h3b, H2_, H3_, 1, 0);

  // mega-fused: layer-4 GEMM -> MFMA score -> softmax+fuse -> VQ -> normalize+pos
  // 16 rows/block, no h3 staging -> ~59.6 KB LDS -> 2 blocks/CU
  l4vq_kernel<<<dim3(B_ / 16), 512, 0, stream>>>(h3b, w4tb, b4, qw1tb, qb1, qw2,
                                                 cb, cbb, cbn2, zb, pos);

  // contrastive rowsum partials
  contrast_mfma_kernel<<<dim3(4, 32, 4), 256, 0, stream>>>(zb, rsP);

  // fused loss reduce + finalize
  final2_kernel<<<dim3(4), 256, 0, stream>>>(rsP, pos, cbsumP, out);
}

// Round 8
// 242.205 us; speedup vs baseline: 1.0122x; 1.0049x over previous
//
#include <hip/hip_runtime.h>
#include <hip/hip_bf16.h>

// Problem constants
#define S_   3
#define B_   4096
#define DIN_ 1024
#define H1_  512
#define H2_  384
#define H3_  256
#define D_   128
#define K_   512
#define C_   3
#define JC_  8               // contrast j-split (B/JC_ = 512 j-rows per block)
#define INV_T 10.0f          // 1/TEMP
#define EPS_  1e-12f
#define EXP10 22026.465794806718f   // exp(1/T), diag(refl) analytically

typedef float f32x4 __attribute__((ext_vector_type(4)));
typedef short bf16x8 __attribute__((ext_vector_type(8)));

__device__ __forceinline__ unsigned short f2bf(float f) {
  unsigned int u = __float_as_uint(f);
  u = (u + 0x7FFF + ((u >> 16) & 1)) >> 16;   // round-to-nearest-even
  return (unsigned short)u;
}

// async 16B-per-lane global -> LDS (wave-uniform base + lane*16 on both sides)
__device__ __forceinline__ void gl2lds16(const unsigned short* g, unsigned short* l) {
  __builtin_amdgcn_global_load_lds(
      (const __attribute__((address_space(1))) void*)g,
      (__attribute__((address_space(3))) void*)l, 16, 0, 0);
}

// ---------------- reduction helpers ----------------
__device__ __forceinline__ float waveReduceSum(float v) {
#pragma unroll
  for (int off = 32; off > 0; off >>= 1) v += __shfl_down(v, off, 64);
  return v;
}

__device__ __forceinline__ float waveXorSum(float v) {
#pragma unroll
  for (int off = 32; off > 0; off >>= 1) v += __shfl_xor(v, off, 64);
  return v;
}

// ------- fused prep: x cvt + weight transposes (w4 plain) + cb norms + qw1^T -----
__global__ __launch_bounds__(256) void prep_kernel(
    const float* __restrict__ x, unsigned short* __restrict__ xb,
    const float* __restrict__ w1, unsigned short* __restrict__ wt1,
    const float* __restrict__ w2, unsigned short* __restrict__ wt2,
    const float* __restrict__ w3, unsigned short* __restrict__ wt3,
    const float* __restrict__ w4, unsigned short* __restrict__ w4tb,
    const float* __restrict__ cb, float* __restrict__ cbn2,
    float* __restrict__ cbsumP, unsigned short* __restrict__ cbb,
    const float* __restrict__ qw1, unsigned short* __restrict__ qw1tb) {
  __shared__ float tt[32][33];
  __shared__ float invn[64];
  const int t = threadIdx.x;
  int blk = blockIdx.x;
  const int NCVT = (S_ * B_ * DIN_) / 1024;   // 12288
  if (blk < NCVT) {
    int i = (blk * 256 + t) * 4;
    float4 v = *(const float4*)(x + i);
    xb[i + 0] = f2bf(v.x); xb[i + 1] = f2bf(v.y);
    xb[i + 2] = f2bf(v.z); xb[i + 3] = f2bf(v.w);
    return;
  }
  blk -= NCVT;
  const int NT = 1536 + 576 + 288 + 96;       // 2496 transpose blocks
  if (blk >= NT) {
    int cblk = blk - NT;
    if (cblk < 24) {
      // ---- codebook norms + bf16 convert + column-sum partials ----
      const int m = cblk >> 3;
      const int k0 = (cblk & 7) * 64;
      const int w = t >> 6, lane = t & 63;
      for (int r = w * 16; r < w * 16 + 16; r++) {
        int k = k0 + r;
        float2 v = *(const float2*)(cb + ((size_t)m * K_ + k) * D_ + lane * 2);
        unsigned short* crow = cbb + ((size_t)m * K_ + k) * D_;
        crow[lane * 2 + 0] = f2bf(v.x);
        crow[lane * 2 + 1] = f2bf(v.y);
        float n2 = waveXorSum(v.x * v.x + v.y * v.y);
        if (lane == 0) {
          cbn2[m * K_ + k] = n2;
          invn[r] = 1.0f / fmaxf(sqrtf(n2), EPS_);
        }
      }
      __syncthreads();
      if (t < D_) {
        float acc = 0.0f;
        for (int r = 0; r < 64; r++)
          acc += cb[((size_t)m * K_ + k0 + r) * D_ + t] * invn[r];
        cbsumP[(size_t)cblk * D_ + t] = acc;
      }
      return;
    }
    // ---- qw1^T bf16 (d-major): 16 blocks of 32x32 ----
    cblk -= 24;                                // [0,16)
    const int kx = cblk & 3, ny = cblk >> 2;
    const int k0 = kx * 32, n0 = ny * 32;
    const int tx = t & 31, ty = t >> 5;
#pragma unroll
    for (int i = 0; i < 4; i++)
      tt[ty + 8 * i][tx] = qw1[(size_t)(k0 + ty + 8 * i) * D_ + n0 + tx];
    __syncthreads();
#pragma unroll
    for (int i = 0; i < 4; i++)
      qw1tb[(size_t)(n0 + ty + 8 * i) * D_ + k0 + tx] = f2bf(tt[tx][ty + 8 * i]);
    return;
  }
  const float* W; unsigned short* Wt; int K, N; int plain = 0;
  if (blk < 1536) { W = w1; Wt = wt1; K = DIN_; N = H1_; }
  else {
    blk -= 1536;
    if (blk < 576) { W = w2; Wt = wt2; K = H1_; N = H2_; }
    else {
      blk -= 576;
      if (blk < 288) { W = w3; Wt = wt3; K = H2_; N = H3_; }
      else { blk -= 288; W = w4; Wt = w4tb; K = H3_; N = D_; plain = 1; }
    }
  }
  const int kx_n = K / 32, ny_n = N / 32;
  const int kx = blk % kx_n;
  const int ny = (blk / kx_n) % ny_n;
  const int s  = blk / (kx_n * ny_n);
  const int k0 = kx * 32, n0 = ny * 32;
  const int tx = t & 31, ty = t >> 5;        // 32 x 8
  const float* Ws = W + (size_t)s * K * N;
  const int nb = N >> 7, kb = K >> 6;
#pragma unroll
  for (int i = 0; i < 4; i++)
    tt[ty + 8 * i][tx] = Ws[(size_t)(k0 + ty + 8 * i) * N + n0 + tx];
  __syncthreads();
  const int k = k0 + tx;
  if (plain) {
    // w4^T: [s][n][k] plain bf16 for direct fragment loads
#pragma unroll
    for (int i = 0; i < 4; i++) {
      int n = n0 + ty + 8 * i;
      Wt[((size_t)(s * D_ + n)) * H3_ + k] = f2bf(tt[tx][ty + 8 * i]);
    }
  } else {
    const int kt = k >> 6, ksl = (k >> 5) & 1;
#pragma unroll
    for (int i = 0; i < 4; i++) {
      int n = n0 + ty + 8 * i;
      size_t dst = ((size_t)(s * nb + (n >> 7)) * kb + kt) * 8192 +
                   (size_t)ksl * 4096 + (size_t)(n & 127) * 32 + (k & 31);
      Wt[dst] = f2bf(tt[tx][ty + 8 * i]);
    }
  }
}

// ---------------- LDS-staged MFMA GEMM, BK=64, async B via global_load_lds -------
__global__ __launch_bounds__(256) void gemm_lds_kernel(
    const unsigned short* __restrict__ A, const unsigned short* __restrict__ Wsw,
    const float* __restrict__ bias, void* __restrict__ Y,
    int K, int N, int relu, int out_f32) {
  const int t = threadIdx.x;
  const int lane = t & 63;
  const int w = t >> 6;
  const int ln = lane & 15, q = lane >> 4;
  const int wm = w >> 1, wn = w & 1;
  const int n0 = blockIdx.x * 128;
  const int mblk = blockIdx.y;
  const int s = mblk >> 6;                  // 4096/64 = 64 m-blocks per source
  const int m0 = mblk * 64;
  const int nb = N >> 7, kb = K >> 6;

  const unsigned short* Ag = A + (size_t)m0 * K;
  const unsigned short* Bt = Wsw + ((size_t)(s * nb + blockIdx.x) * kb) * 8192;
  const float* bs = bias + (size_t)s * N;

  __shared__ unsigned short Asm[2 * 64 * 32];     // 8 KB (two 32-k halves)
  __shared__ unsigned short Bsm[2 * 8192];        // 32 KB double buffer

  const int arow0 = t >> 3, ak8 = t & 7;
  const int aL0 = (ak8 >> 2) * 2048 + arow0 * 32 + (ak8 & 3) * 8;
  const size_t gA0 = (size_t)arow0 * K + ak8 * 8;

  // preload A regs (tile 0) + issue async B tile 0
  bf16x8 ra0 = *(const bf16x8*)(Ag + gA0);
  bf16x8 ra1 = *(const bf16x8*)(Ag + gA0 + (size_t)32 * K);
#pragma unroll
  for (int p = 0; p < 4; p++)
    gl2lds16(Bt + (size_t)(p * 256 + t) * 8, &Bsm[(size_t)(p * 256 + t) * 8]);

  f32x4 acc[2][4];
#pragma unroll
  for (int i = 0; i < 2; i++)
#pragma unroll
    for (int j = 0; j < 4; j++) acc[i][j] = (f32x4){0.f, 0.f, 0.f, 0.f};

  for (int kt = 0; kt < kb; kt++) {
    *(bf16x8*)&Asm[aL0] = ra0;
    *(bf16x8*)&Asm[aL0 + 1024] = ra1;
    __syncthreads();                       // drains vmcnt: B tile kt complete
    const unsigned short* Bcur = &Bsm[(kt & 1) * 8192];
    if (kt + 1 < kb) {
      const unsigned short* Bn = Bt + (size_t)(kt + 1) * 8192;
      unsigned short* Bd = &Bsm[((kt + 1) & 1) * 8192];
#pragma unroll
      for (int p = 0; p < 4; p++)
        gl2lds16(Bn + (size_t)(p * 256 + t) * 8, Bd + (size_t)(p * 256 + t) * 8);
      const size_t g = gA0 + (size_t)(kt + 1) * 64;
      ra0 = *(const bf16x8*)(Ag + g);
      ra1 = *(const bf16x8*)(Ag + g + (size_t)32 * K);
    }
    bf16x8 af[2][2], bf[4][2];
#pragma unroll
    for (int ti = 0; ti < 2; ti++)
#pragma unroll
      for (int ksl = 0; ksl < 2; ksl++)
        af[ti][ksl] = *(const bf16x8*)&Asm[ksl * 2048 + (wm * 32 + ti * 16 + ln) * 32 + q * 8];
#pragma unroll
    for (int tj = 0; tj < 4; tj++)
#pragma unroll
      for (int ksl = 0; ksl < 2; ksl++)
        bf[tj][ksl] = *(const bf16x8*)&Bcur[ksl * 4096 + (wn * 64 + tj * 16 + ln) * 32 + q * 8];
#pragma unroll
    for (int ksl = 0; ksl < 2; ksl++)
#pragma unroll
      for (int ti = 0; ti < 2; ti++)
#pragma unroll
        for (int tj = 0; tj < 4; tj++)
          acc[ti][tj] = __builtin_amdgcn_mfma_f32_16x16x32_bf16(af[ti][ksl], bf[tj][ksl], acc[ti][tj], 0, 0, 0);
    __syncthreads();
  }

#pragma unroll
  for (int ti = 0; ti < 2; ti++)
#pragma unroll
    for (int tj = 0; tj < 4; tj++) {
      const int cc = n0 + wn * 64 + tj * 16 + ln;
      const float bv = bs[cc];
#pragma unroll
      for (int reg = 0; reg < 4; reg++) {
        const int r = m0 + wm * 32 + ti * 16 + q * 4 + reg;
        float v = acc[ti][tj][reg] + bv;
        if (relu) v = fmaxf(v, 0.0f);
        if (out_f32) ((float*)Y)[(size_t)r * N + cc] = v;
        else ((unsigned short*)Y)[(size_t)r * N + cc] = f2bf(v);
      }
    }
}

// -------- mega-fused: layer-4 GEMM -> MFMA score -> softmax+fuse -> VQ -> norm ----
// One block per 16 batch rows, 512 threads (8 waves). h3 staged in LDS once;
// emb computed in-kernel (never touches global); everything stays in LDS.
__global__ __launch_bounds__(512) void l4vq_kernel(
    const unsigned short* __restrict__ h3b, const unsigned short* __restrict__ w4tb,
    const float* __restrict__ b4, const unsigned short* __restrict__ qw1tb,
    const float* __restrict__ qb1, const float* __restrict__ qw2,
    const float* __restrict__ cb, const unsigned short* __restrict__ cbb,
    const float* __restrict__ cbn2,
    unsigned short* __restrict__ zb, float* __restrict__ pos) {
  const int b0 = blockIdx.x * 16;
  const int t = threadIdx.x;
  const int w = t >> 6, lane = t & 63;
  const int ln = lane & 15, q = lane >> 4;

  __shared__ unsigned short h3s[48][264]; // h3 rows bf16 (padded)        (25.3 KB)
  __shared__ float e[48][D_];             // emb rows f32, r = s*16+bi    (24 KB)
  __shared__ unsigned short ebb[48][136]; // emb rows bf16 (padded)       (12.75 KB)
  __shared__ float qf[16][D_];            // fused -> qsum -> z1          (8 KB)
  __shared__ float resv[16][D_];          // residual f32                 (8 KB)
  __shared__ unsigned short resb[16][136];// residual bf16 (padded)       (4.25 KB)
  __shared__ float red2[8][48];
  __shared__ float sc[48];
  __shared__ float candd[8][16];
  __shared__ int candk[8][16];
  __shared__ int bestk[16];

  // B fragments of qw1^T for this wave's 16 score-cols (global, L2-hot)
  bf16x8 bq[4];
  {
    const unsigned short* qp = qw1tb + (size_t)(w * 16 + ln) * D_;
#pragma unroll
    for (int ks = 0; ks < 4; ks++)
      bq[ks] = *(const bf16x8*)(qp + ks * 32 + q * 8);
  }

  // ---- stage h3 rows (48 x 256 bf16) ----
#pragma unroll
  for (int p = 0; p < 3; p++) {
    int f = p * 512 + t;                  // 1536 fragments of 8 bf16
    int r = f >> 5, kf = f & 31;
    int s = r >> 4, bi = r & 15;
    *(bf16x8*)&h3s[r][kf * 8] =
        *(const bf16x8*)(h3b + ((size_t)(s * B_ + b0 + bi)) * H3_ + kf * 8);
  }
  __syncthreads();

  // ---- layer-4 GEMM: emb[s][bi][col] for col = w*16+ln, bi = q*4+reg ----
  {
    const int col = w * 16 + ln;
#pragma unroll
    for (int s = 0; s < 3; s++) {
      f32x4 oacc = (f32x4){0.f, 0.f, 0.f, 0.f};
      const unsigned short* wp = w4tb + ((size_t)(s * D_ + col)) * H3_;
#pragma unroll
      for (int ks = 0; ks < 8; ks++) {
        bf16x8 bfrag = *(const bf16x8*)(wp + ks * 32 + q * 8);
        bf16x8 afrag = *(const bf16x8*)&h3s[s * 16 + ln][ks * 32 + q * 8];
        oacc = __builtin_amdgcn_mfma_f32_16x16x32_bf16(afrag, bfrag, oacc, 0, 0, 0);
      }
      const float bv = b4[s * D_ + col];
#pragma unroll
      for (int reg = 0; reg < 4; reg++) {
        int r = s * 16 + q * 4 + reg;
        float v = oacc[reg] + bv;
        e[r][col] = v;
        ebb[r][col] = f2bf(v);
      }
    }
  }
  __syncthreads();

  // ---- attention scores via MFMA: h[r][col] for col = w*16+ln ----
  {
    f32x4 sacc[3];
#pragma unroll
    for (int rt = 0; rt < 3; rt++) sacc[rt] = (f32x4){0.f, 0.f, 0.f, 0.f};
#pragma unroll
    for (int ks = 0; ks < 4; ks++) {
#pragma unroll
      for (int rt = 0; rt < 3; rt++) {
        bf16x8 a = *(const bf16x8*)&ebb[rt * 16 + ln][ks * 32 + q * 8];
        sacc[rt] = __builtin_amdgcn_mfma_f32_16x16x32_bf16(a, bq[ks], sacc[rt], 0, 0, 0);
      }
    }
    const int col = w * 16 + ln;
    const float qb = qb1[col], q2v = qw2[col];
#pragma unroll
    for (int rt = 0; rt < 3; rt++)
#pragma unroll
      for (int reg = 0; reg < 4; reg++) {
        float v = tanhf(sacc[rt][reg] + qb) * q2v;
#pragma unroll
        for (int off = 8; off > 0; off >>= 1) v += __shfl_xor(v, off, 16);
        if (ln == 0) red2[w][rt * 16 + q * 4 + reg] = v;
      }
  }
  __syncthreads();
  if (t < 48) {
    float s = 0.f;
#pragma unroll
    for (int ww = 0; ww < 8; ww++) s += red2[ww][t];
    sc[t] = s;                                 // sc[r], r = s*16+bi
  }
  __syncthreads();

  // ---- softmax over sources + fuse -> residual buffers ----
#pragma unroll
  for (int p = 0; p < 4; p++) {
    int idx = p * 512 + t;
    int bi = idx >> 7, dd = idx & 127;
    float s0 = sc[bi], s1 = sc[16 + bi], s2 = sc[32 + bi];
    float mx = fmaxf(s0, fmaxf(s1, s2));
    float e0 = __expf(s0 - mx), e1 = __expf(s1 - mx), e2 = __expf(s2 - mx);
    float inv = 1.0f / (e0 + e1 + e2);
    float fv = (e0 * e[bi][dd] + e1 * e[16 + bi][dd] + e2 * e[32 + bi][dd]) * inv;
    qf[bi][dd] = fv;
    resv[bi][dd] = fv;
    resb[bi][dd] = f2bf(fv);
  }
  __syncthreads();

  // ---- residual VQ (MFMA distance GEMM), 3 codebooks ----
  for (int c = 0; c < C_; c++) {
    bf16x8 a[4];
#pragma unroll
    for (int ks = 0; ks < 4; ks++)
      a[ks] = *(const bf16x8*)&resb[ln][ks * 32 + q * 8];
    f32x4 acc[4];
#pragma unroll
    for (int tt = 0; tt < 4; tt++) acc[tt] = (f32x4){0.f, 0.f, 0.f, 0.f};
#pragma unroll
    for (int tt = 0; tt < 4; tt++) {
      const int n = w * 64 + tt * 16 + ln;
      const unsigned short* bp = cbb + ((size_t)c * K_ + n) * D_;
#pragma unroll
      for (int ks = 0; ks < 4; ks++) {
        bf16x8 b = *(const bf16x8*)(bp + ks * 32 + q * 8);
        acc[tt] = __builtin_amdgcn_mfma_f32_16x16x32_bf16(a[ks], b, acc[tt], 0, 0, 0);
      }
    }
    float bd[4]; int bk[4];
#pragma unroll
    for (int reg = 0; reg < 4; reg++) { bd[reg] = 3.4e38f; bk[reg] = 0x7fffffff; }
#pragma unroll
    for (int tt = 0; tt < 4; tt++) {
      const int col = w * 64 + tt * 16 + ln;
      const float n2 = cbn2[c * K_ + col];
#pragma unroll
      for (int reg = 0; reg < 4; reg++) {
        float dist = n2 - 2.0f * acc[tt][reg];
        if (dist < bd[reg] || (dist == bd[reg] && col < bk[reg])) { bd[reg] = dist; bk[reg] = col; }
      }
    }
#pragma unroll
    for (int reg = 0; reg < 4; reg++) {
#pragma unroll
      for (int off = 8; off > 0; off >>= 1) {
        float d1 = __shfl_down(bd[reg], off, 16);
        int k1 = __shfl_down(bk[reg], off, 16);
        if (d1 < bd[reg] || (d1 == bd[reg] && k1 < bk[reg])) { bd[reg] = d1; bk[reg] = k1; }
      }
      if (ln == 0) { candd[w][q * 4 + reg] = bd[reg]; candk[w][q * 4 + reg] = bk[reg]; }
    }
    __syncthreads();
    if (w == 0) {
      int row = lane >> 2, g = lane & 3;
      float d0 = candd[2 * g][row]; int k0 = candk[2 * g][row];
      float d1 = candd[2 * g + 1][row]; int k1 = candk[2 * g + 1][row];
      if (d1 < d0 || (d1 == d0 && k1 < k0)) { d0 = d1; k0 = k1; }
#pragma unroll
      for (int off = 2; off > 0; off >>= 1) {
        float dn = __shfl_down(d0, off, 4);
        int kn = __shfl_down(k0, off, 4);
        if (dn < d0 || (dn == d0 && kn < k0)) { d0 = dn; k0 = kn; }
      }
      if (g == 0) bestk[row] = k0;
    }
    __syncthreads();
    {
      int idx = t * 4;
      int r = idx >> 7, dd = idx & 127;
      const float4 qv = *(const float4*)(cb + ((size_t)c * K_ + bestk[r]) * D_ + dd);
      float4 rv = *(float4*)&resv[r][dd];
      rv.x -= qv.x; rv.y -= qv.y; rv.z -= qv.z; rv.w -= qv.w;
      *(float4*)&resv[r][dd] = rv;
      resb[r][dd + 0] = f2bf(rv.x); resb[r][dd + 1] = f2bf(rv.y);
      resb[r][dd + 2] = f2bf(rv.z); resb[r][dd + 3] = f2bf(rv.w);
    }
    __syncthreads();
  }

  // ---- qsum = fused - res (in LDS) ----
  {
    int idx = t * 4;
    int r = idx >> 7, dd = idx & 127;
    float4 f = *(float4*)&qf[r][dd];
    float4 rv = *(float4*)&resv[r][dd];
    f.x -= rv.x; f.y -= rv.y; f.z -= rv.z; f.w -= rv.w;
    *(float4*)&qf[r][dd] = f;
  }
  __syncthreads();

  // ---- z1 = normalize(qsum): 8 waves x 2 rows ----
#pragma unroll
  for (int rr = 0; rr < 2; rr++) {
    int r = w * 2 + rr;
    float2 v = *(const float2*)&qf[r][lane * 2];
    float n2 = waveXorSum(v.x * v.x + v.y * v.y);
    float inv = 1.0f / fmaxf(sqrtf(n2), EPS_);
    float zx = v.x * inv, zy = v.y * inv;
    zb[(size_t)(b0 + r) * D_ + lane * 2 + 0] = f2bf(zx);
    zb[(size_t)(b0 + r) * D_ + lane * 2 + 1] = f2bf(zy);
    qf[r][lane * 2] = zx; qf[r][lane * 2 + 1] = zy;   // keep z1 f32 for pos
  }
  __syncthreads();

  // ---- z2 = normalize(emb) + pos = z1.z2: 8 waves x 6 rows ----
#pragma unroll
  for (int rr = 0; rr < 6; rr++) {
    int r = w * 6 + rr;
    int s = r >> 4, bi = r & 15;
    float2 v = *(const float2*)&e[r][lane * 2];
    float n2 = waveXorSum(v.x * v.x + v.y * v.y);
    float inv = 1.0f / fmaxf(sqrtf(n2), EPS_);
    float zx = v.x * inv, zy = v.y * inv;
    size_t gb = (size_t)(1 + s) * B_ + b0 + bi;
    zb[gb * D_ + lane * 2 + 0] = f2bf(zx);
    zb[gb * D_ + lane * 2 + 1] = f2bf(zy);
    float2 a1 = *(const float2*)&qf[bi][lane * 2];
    float dsum = waveXorSum(a1.x * zx + a1.y * zy);
    if (lane == 0) pos[s * B_ + b0 + bi] = dsum;
  }
}

// ---------------- contrastive exp-rowsums: LDS-staged B tiles, JC_=8 ------------
__global__ __launch_bounds__(256) void contrast_mfma_kernel(
    const unsigned short* __restrict__ zb, float* __restrict__ rsP) {
  const int jc = blockIdx.x, ib = blockIdx.y, m = blockIdx.z;
  const int t = threadIdx.x;
  const int w = t >> 6, lane = t & 63;
  const int ln = lane & 15, q = lane >> 4;
  const int i0 = ib * 128 + w * 32;
  const unsigned short* Za = zb;
  const unsigned short* Zm = zb + (size_t)m * B_ * D_;
  const int JROWS = B_ / JC_;             // 512 j-rows per block
  const int NJT = JROWS / 64;             // 8 tiles

  __shared__ unsigned short Zsm[64 * 136];

  bf16x8 a[2][4];
#pragma unroll
  for (int si = 0; si < 2; si++)
#pragma unroll
    for (int ks = 0; ks < 4; ks++)
      a[si][ks] = *(const bf16x8*)(Za + (size_t)(i0 + si * 16 + ln) * D_ + ks * 32 + q * 8);

  const unsigned short* tb = Zm + (size_t)(jc * JROWS) * D_;
  bf16x8 rz[4];
#pragma unroll
  for (int p = 0; p < 4; p++)
    rz[p] = *(const bf16x8*)(tb + t * 8 + p * 2048);

  float e[2][4] = {};
  for (int jt = 0; jt < NJT; jt++) {
#pragma unroll
    for (int p = 0; p < 4; p++) {
      int c = t + p * 256;
      *(bf16x8*)&Zsm[(c >> 4) * 136 + (c & 15) * 8] = rz[p];
    }
    __syncthreads();
    if (jt + 1 < NJT) {
      const unsigned short* tn = Zm + (size_t)(jc * JROWS + (jt + 1) * 64) * D_;
#pragma unroll
      for (int p = 0; p < 4; p++)
        rz[p] = *(const bf16x8*)(tn + t * 8 + p * 2048);
    }
    f32x4 acc[2][4];
#pragma unroll
    for (int si = 0; si < 2; si++)
#pragma unroll
      for (int tj = 0; tj < 4; tj++) acc[si][tj] = (f32x4){0.f, 0.f, 0.f, 0.f};
#pragma unroll
    for (int tj = 0; tj < 4; tj++) {
      bf16x8 b[4];
#pragma unroll
      for (int ks = 0; ks < 4; ks++)
        b[ks] = *(const bf16x8*)&Zsm[(tj * 16 + ln) * 136 + ks * 32 + q * 8];
#pragma unroll
      for (int ks = 0; ks < 4; ks++) {
        acc[0][tj] = __builtin_amdgcn_mfma_f32_16x16x32_bf16(a[0][ks], b[ks], acc[0][tj], 0, 0, 0);
        acc[1][tj] = __builtin_amdgcn_mfma_f32_16x16x32_bf16(a[1][ks], b[ks], acc[1][tj], 0, 0, 0);
      }
    }
#pragma unroll
    for (int si = 0; si < 2; si++)
#pragma unroll
      for (int reg = 0; reg < 4; reg++) {
        float s = 0.f;
#pragma unroll
        for (int tj = 0; tj < 4; tj++) s += __expf(acc[si][tj][reg] * INV_T);
        e[si][reg] += s;
      }
    __syncthreads();
  }
#pragma unroll
  for (int si = 0; si < 2; si++)
#pragma unroll
    for (int reg = 0; reg < 4; reg++) {
#pragma unroll
      for (int off = 8; off > 0; off >>= 1)
        e[si][reg] += __shfl_xor(e[si][reg], off, 16);
    }
  if (ln == 0) {
#pragma unroll
    for (int si = 0; si < 2; si++)
#pragma unroll
      for (int reg = 0; reg < 4; reg++)
        rsP[((size_t)m * JC_ + jc) * B_ + i0 + si * 16 + q * 4 + reg] = e[si][reg];
  }
}

// ---------------- fused loss reduce + finalize (4 blocks) ----------------
__global__ __launch_bounds__(256) void final2_kernel(const float* __restrict__ rsP,
                                                     const float* __restrict__ pos,
                                                     const float* __restrict__ cbsumP,
                                                     float* __restrict__ out) {
  const int blk = blockIdx.x;
  const int t = threadIdx.x;
  __shared__ float red[4];
  if (blk == 0) {
    float acc = 0.0f;
    if (t < D_) {
#pragma unroll
      for (int m = 0; m < C_; m++) {
        float v = 0.0f;
#pragma unroll
        for (int b8 = 0; b8 < 8; b8++) v += cbsumP[(size_t)(m * 8 + b8) * D_ + t];
        acc += v * v;
      }
    }
    float v = waveReduceSum(acc);
    if ((t & 63) == 0) red[t >> 6] = v;
    __syncthreads();
    if (t == 0) {
      out[0] = (red[0] + red[1] + red[2] + red[3]) * (1.0f / (3.0f * 512.0f * 512.0f));
      out[1] = 0.0f;
    }
  } else {
    const int s = blk - 1;
    float acc = 0.0f;
    for (int it = 0; it < 16; it++) {
      const int i = it * 256 + t;
      float denom = -EXP10;
#pragma unroll
      for (int jc = 0; jc < JC_; jc++) {
        denom += rsP[(size_t)jc * B_ + i];
        denom += rsP[((size_t)(1 + s) * JC_ + jc) * B_ + i];
      }
      acc += logf(denom) - pos[s * B_ + i] * INV_T;
    }
    float v = waveReduceSum(acc);
    if ((t & 63) == 0) red[t >> 6] = v;
    __syncthreads();
    if (t == 0)
      out[2 + s] = (red[0] + red[1] + red[2] + red[3]) * (1.0f / 4096.0f);
  }
}

extern "C" void kernel_launch(void* const* d_in, const int* in_sizes, int n_in,
                              void* d_out, int out_size, void* d_ws, size_t ws_size,
                              hipStream_t stream) {
  const float* x    = (const float*)d_in[0];
  const float* w1   = (const float*)d_in[1];
  const float* b1   = (const float*)d_in[2];
  const float* w2   = (const float*)d_in[3];
  const float* b2   = (const float*)d_in[4];
  const float* w3   = (const float*)d_in[5];
  const float* b3   = (const float*)d_in[6];
  const float* w4   = (const float*)d_in[7];
  const float* b4   = (const float*)d_in[8];
  const float* qw1  = (const float*)d_in[9];
  const float* qb1  = (const float*)d_in[10];
  const float* qw2  = (const float*)d_in[11];
  const float* cb   = (const float*)d_in[12];
  float* out = (float*)d_out;
  char* base = (char*)d_ws;

  size_t o = 0;
  auto alloc = [&](size_t bytes) { size_t r = o; o += (bytes + 255) & ~(size_t)255; return r; };
  size_t o_xb   = alloc((size_t)S_ * B_ * DIN_ * 2);
  size_t o_wt1  = alloc((size_t)S_ * H1_ * DIN_ * 2);
  size_t o_wt2  = alloc((size_t)S_ * H2_ * H1_ * 2);
  size_t o_wt3  = alloc((size_t)S_ * H3_ * H2_ * 2);
  size_t o_w4t  = alloc((size_t)S_ * D_ * H3_ * 2);
  size_t o_h1b  = alloc((size_t)S_ * B_ * H1_ * 2);
  size_t o_h2b  = alloc((size_t)S_ * B_ * H2_ * 2);
  size_t o_h3b  = alloc((size_t)S_ * B_ * H3_ * 2);
  size_t o_zb   = alloc((size_t)4 * B_ * D_ * 2);
  size_t o_cbn2 = alloc((size_t)C_ * K_ * 4);
  size_t o_cbb  = alloc((size_t)C_ * K_ * D_ * 2);
  size_t o_rsP  = alloc((size_t)4 * JC_ * B_ * 4);
  size_t o_cbsP = alloc((size_t)C_ * 8 * D_ * 4);
  size_t o_pos  = alloc((size_t)S_ * B_ * 4);
  size_t o_q1t  = alloc((size_t)D_ * D_ * 2);
  (void)ws_size; (void)in_sizes; (void)n_in; (void)out_size;

  unsigned short* xb  = (unsigned short*)(base + o_xb);
  unsigned short* wt1 = (unsigned short*)(base + o_wt1);
  unsigned short* wt2 = (unsigned short*)(base + o_wt2);
  unsigned short* wt3 = (unsigned short*)(base + o_wt3);
  unsigned short* w4tb= (unsigned short*)(base + o_w4t);
  unsigned short* h1b = (unsigned short*)(base + o_h1b);
  unsigned short* h2b = (unsigned short*)(base + o_h2b);
  unsigned short* h3b = (unsigned short*)(base + o_h3b);
  unsigned short* zb = (unsigned short*)(base + o_zb);
  float* cbn2  = (float*)(base + o_cbn2);
  unsigned short* cbb = (unsigned short*)(base + o_cbb);
  float* rsP   = (float*)(base + o_rsP);
  float* cbsumP= (float*)(base + o_cbsP);
  float* pos   = (float*)(base + o_pos);
  unsigned short* qw1tb = (unsigned short*)(base + o_q1t);

  // fused prep: x->bf16 + weight transposes + codebook norms + qw1^T (one launch)
  const int prep_blocks = (S_ * B_ * DIN_) / 1024 + 1536 + 576 + 288 + 96 + C_ * 8 + 16;
  prep_kernel<<<dim3(prep_blocks), 256, 0, stream>>>(x, xb, w1, wt1, w2, wt2, w3, wt3, w4, w4tb,
                                                     cb, cbn2, cbsumP, cbb, qw1, qw1tb);

  // encoder MLP layers 1-3 via LDS-staged MFMA (BK=64, async B staging)
  const int Mtot = S_ * B_;
  gemm_lds_kernel<<<dim3(H1_ / 128, Mtot / 64), 256, 0, stream>>>(xb, wt1, b1, h1b, DIN_, H1_, 1, 0);
  gemm_lds_kernel<<<dim3(H2_ / 128, Mtot / 64), 256, 0, stream>>>(h1b, wt2, b2, h2b, H1_, H2_, 1, 0);
  gemm_lds_kernel<<<dim3(H3_ / 128, Mtot / 64), 256, 0, stream>>>(h2b, wt3, b3, h3b, H2_, H3_, 1, 0);

  // mega-fused: layer-4 GEMM -> MFMA score -> softmax+fuse -> VQ -> normalize+pos
  l4vq_kernel<<<dim3(B_ / 16), 512, 0, stream>>>(h3b, w4tb, b4, qw1tb, qb1, qw2,
                                                 cb, cbb, cbn2, zb, pos);

  // contrastive rowsum partials (JC_=8 -> 1024 blocks -> 4 blocks/CU)
  contrast_mfma_kernel<<<dim3(JC_, 32, 4), 256, 0, stream>>>(zb, rsP);

  // fused loss reduce + finalize
  final2_kernel<<<dim3(4), 256, 0, stream>>>(rsP, pos, cbsumP, out);
}

// Round 9
// 239.017 us; speedup vs baseline: 1.0257x; 1.0133x over previous
//
#include <hip/hip_runtime.h>
#include <hip/hip_bf16.h>

// Problem constants
#define S_   3
#define B_   4096
#define DIN_ 1024
#define H1_  512
#define H2_  384
#define H3_  256
#define D_   128
#define K_   512
#define C_   3
#define JC_  8               // contrast j-split (B/JC_ = 512 j-rows per block)
#define INV_T 10.0f          // 1/TEMP
#define EPS_  1e-12f
#define EXP10 22026.465794806718f   // exp(1/T), diag(refl) analytically

typedef float f32x4 __attribute__((ext_vector_type(4)));
typedef short bf16x8 __attribute__((ext_vector_type(8)));

__device__ __forceinline__ unsigned short f2bf(float f) {
  unsigned int u = __float_as_uint(f);
  u = (u + 0x7FFF + ((u >> 16) & 1)) >> 16;   // round-to-nearest-even
  return (unsigned short)u;
}

// async 16B-per-lane global -> LDS (wave-uniform base + lane*16 on both sides)
__device__ __forceinline__ void gl2lds16(const unsigned short* g, unsigned short* l) {
  __builtin_amdgcn_global_load_lds(
      (const __attribute__((address_space(1))) void*)g,
      (__attribute__((address_space(3))) void*)l, 16, 0, 0);
}

// ---------------- reduction helpers ----------------
__device__ __forceinline__ float waveReduceSum(float v) {
#pragma unroll
  for (int off = 32; off > 0; off >>= 1) v += __shfl_down(v, off, 64);
  return v;
}

__device__ __forceinline__ float waveXorSum(float v) {
#pragma unroll
  for (int off = 32; off > 0; off >>= 1) v += __shfl_xor(v, off, 64);
  return v;
}

// ------- fused prep: x cvt + weight transposes (w4 plain) + cb norms + qw1^T -----
__global__ __launch_bounds__(256) void prep_kernel(
    const float* __restrict__ x, unsigned short* __restrict__ xb,
    const float* __restrict__ w1, unsigned short* __restrict__ wt1,
    const float* __restrict__ w2, unsigned short* __restrict__ wt2,
    const float* __restrict__ w3, unsigned short* __restrict__ wt3,
    const float* __restrict__ w4, unsigned short* __restrict__ w4tb,
    const float* __restrict__ cb, float* __restrict__ cbn2,
    float* __restrict__ cbsumP, unsigned short* __restrict__ cbb,
    const float* __restrict__ qw1, unsigned short* __restrict__ qw1tb) {
  __shared__ float tt[32][33];
  __shared__ float invn[64];
  const int t = threadIdx.x;
  int blk = blockIdx.x;
  const int NCVT = (S_ * B_ * DIN_) / 1024;   // 12288
  if (blk < NCVT) {
    int i = (blk * 256 + t) * 4;
    float4 v = *(const float4*)(x + i);
    xb[i + 0] = f2bf(v.x); xb[i + 1] = f2bf(v.y);
    xb[i + 2] = f2bf(v.z); xb[i + 3] = f2bf(v.w);
    return;
  }
  blk -= NCVT;
  const int NT = 1536 + 576 + 288 + 96;       // 2496 transpose blocks
  if (blk >= NT) {
    int cblk = blk - NT;
    if (cblk < 24) {
      // ---- codebook norms + bf16 convert + column-sum partials ----
      const int m = cblk >> 3;
      const int k0 = (cblk & 7) * 64;
      const int w = t >> 6, lane = t & 63;
      for (int r = w * 16; r < w * 16 + 16; r++) {
        int k = k0 + r;
        float2 v = *(const float2*)(cb + ((size_t)m * K_ + k) * D_ + lane * 2);
        unsigned short* crow = cbb + ((size_t)m * K_ + k) * D_;
        crow[lane * 2 + 0] = f2bf(v.x);
        crow[lane * 2 + 1] = f2bf(v.y);
        float n2 = waveXorSum(v.x * v.x + v.y * v.y);
        if (lane == 0) {
          cbn2[m * K_ + k] = n2;
          invn[r] = 1.0f / fmaxf(sqrtf(n2), EPS_);
        }
      }
      __syncthreads();
      if (t < D_) {
        float acc = 0.0f;
        for (int r = 0; r < 64; r++)
          acc += cb[((size_t)m * K_ + k0 + r) * D_ + t] * invn[r];
        cbsumP[(size_t)cblk * D_ + t] = acc;
      }
      return;
    }
    // ---- qw1^T bf16 (d-major): 16 blocks of 32x32 ----
    cblk -= 24;                                // [0,16)
    const int kx = cblk & 3, ny = cblk >> 2;
    const int k0 = kx * 32, n0 = ny * 32;
    const int tx = t & 31, ty = t >> 5;
#pragma unroll
    for (int i = 0; i < 4; i++)
      tt[ty + 8 * i][tx] = qw1[(size_t)(k0 + ty + 8 * i) * D_ + n0 + tx];
    __syncthreads();
#pragma unroll
    for (int i = 0; i < 4; i++)
      qw1tb[(size_t)(n0 + ty + 8 * i) * D_ + k0 + tx] = f2bf(tt[tx][ty + 8 * i]);
    return;
  }
  const float* W; unsigned short* Wt; int K, N; int plain = 0;
  if (blk < 1536) { W = w1; Wt = wt1; K = DIN_; N = H1_; }
  else {
    blk -= 1536;
    if (blk < 576) { W = w2; Wt = wt2; K = H1_; N = H2_; }
    else {
      blk -= 576;
      if (blk < 288) { W = w3; Wt = wt3; K = H2_; N = H3_; }
      else { blk -= 288; W = w4; Wt = w4tb; K = H3_; N = D_; plain = 1; }
    }
  }
  const int kx_n = K / 32, ny_n = N / 32;
  const int kx = blk % kx_n;
  const int ny = (blk / kx_n) % ny_n;
  const int s  = blk / (kx_n * ny_n);
  const int k0 = kx * 32, n0 = ny * 32;
  const int tx = t & 31, ty = t >> 5;        // 32 x 8
  const float* Ws = W + (size_t)s * K * N;
  const int nb = N >> 7, kb = K >> 6;
#pragma unroll
  for (int i = 0; i < 4; i++)
    tt[ty + 8 * i][tx] = Ws[(size_t)(k0 + ty + 8 * i) * N + n0 + tx];
  __syncthreads();
  const int k = k0 + tx;
  if (plain) {
    // w4^T: [s][n][k] plain bf16 for direct fragment loads
#pragma unroll
    for (int i = 0; i < 4; i++) {
      int n = n0 + ty + 8 * i;
      Wt[((size_t)(s * D_ + n)) * H3_ + k] = f2bf(tt[tx][ty + 8 * i]);
    }
  } else {
    const int kt = k >> 6, ksl = (k >> 5) & 1;
#pragma unroll
    for (int i = 0; i < 4; i++) {
      int n = n0 + ty + 8 * i;
      size_t dst = ((size_t)(s * nb + (n >> 7)) * kb + kt) * 8192 +
                   (size_t)ksl * 4096 + (size_t)(n & 127) * 32 + (k & 31);
      Wt[dst] = f2bf(tt[tx][ty + 8 * i]);
    }
  }
}

// ---------------- LDS-staged MFMA GEMM, BK=64, async B via global_load_lds -------
__global__ __launch_bounds__(256) void gemm_lds_kernel(
    const unsigned short* __restrict__ A, const unsigned short* __restrict__ Wsw,
    const float* __restrict__ bias, void* __restrict__ Y,
    int K, int N, int relu, int out_f32) {
  const int t = threadIdx.x;
  const int lane = t & 63;
  const int w = t >> 6;
  const int ln = lane & 15, q = lane >> 4;
  const int wm = w >> 1, wn = w & 1;
  const int n0 = blockIdx.x * 128;
  const int mblk = blockIdx.y;
  const int s = mblk >> 6;                  // 4096/64 = 64 m-blocks per source
  const int m0 = mblk * 64;
  const int nb = N >> 7, kb = K >> 6;

  const unsigned short* Ag = A + (size_t)m0 * K;
  const unsigned short* Bt = Wsw + ((size_t)(s * nb + blockIdx.x) * kb) * 8192;
  const float* bs = bias + (size_t)s * N;

  __shared__ unsigned short Asm[2 * 64 * 32];     // 8 KB (two 32-k halves)
  __shared__ unsigned short Bsm[2 * 8192];        // 32 KB double buffer

  const int arow0 = t >> 3, ak8 = t & 7;
  const int aL0 = (ak8 >> 2) * 2048 + arow0 * 32 + (ak8 & 3) * 8;
  const size_t gA0 = (size_t)arow0 * K + ak8 * 8;

  // preload A regs (tile 0) + issue async B tile 0
  bf16x8 ra0 = *(const bf16x8*)(Ag + gA0);
  bf16x8 ra1 = *(const bf16x8*)(Ag + gA0 + (size_t)32 * K);
#pragma unroll
  for (int p = 0; p < 4; p++)
    gl2lds16(Bt + (size_t)(p * 256 + t) * 8, &Bsm[(size_t)(p * 256 + t) * 8]);

  f32x4 acc[2][4];
#pragma unroll
  for (int i = 0; i < 2; i++)
#pragma unroll
    for (int j = 0; j < 4; j++) acc[i][j] = (f32x4){0.f, 0.f, 0.f, 0.f};

  for (int kt = 0; kt < kb; kt++) {
    *(bf16x8*)&Asm[aL0] = ra0;
    *(bf16x8*)&Asm[aL0 + 1024] = ra1;
    __syncthreads();                       // drains vmcnt: B tile kt complete
    const unsigned short* Bcur = &Bsm[(kt & 1) * 8192];
    if (kt + 1 < kb) {
      const unsigned short* Bn = Bt + (size_t)(kt + 1) * 8192;
      unsigned short* Bd = &Bsm[((kt + 1) & 1) * 8192];
#pragma unroll
      for (int p = 0; p < 4; p++)
        gl2lds16(Bn + (size_t)(p * 256 + t) * 8, Bd + (size_t)(p * 256 + t) * 8);
      const size_t g = gA0 + (size_t)(kt + 1) * 64;
      ra0 = *(const bf16x8*)(Ag + g);
      ra1 = *(const bf16x8*)(Ag + g + (size_t)32 * K);
    }
    bf16x8 af[2][2], bf[4][2];
#pragma unroll
    for (int ti = 0; ti < 2; ti++)
#pragma unroll
      for (int ksl = 0; ksl < 2; ksl++)
        af[ti][ksl] = *(const bf16x8*)&Asm[ksl * 2048 + (wm * 32 + ti * 16 + ln) * 32 + q * 8];
#pragma unroll
    for (int tj = 0; tj < 4; tj++)
#pragma unroll
      for (int ksl = 0; ksl < 2; ksl++)
        bf[tj][ksl] = *(const bf16x8*)&Bcur[ksl * 4096 + (wn * 64 + tj * 16 + ln) * 32 + q * 8];
#pragma unroll
    for (int ksl = 0; ksl < 2; ksl++)
#pragma unroll
      for (int ti = 0; ti < 2; ti++)
#pragma unroll
        for (int tj = 0; tj < 4; tj++)
          acc[ti][tj] = __builtin_amdgcn_mfma_f32_16x16x32_bf16(af[ti][ksl], bf[tj][ksl], acc[ti][tj], 0, 0, 0);
    __syncthreads();
  }

#pragma unroll
  for (int ti = 0; ti < 2; ti++)
#pragma unroll
    for (int tj = 0; tj < 4; tj++) {
      const int cc = n0 + wn * 64 + tj * 16 + ln;
      const float bv = bs[cc];
#pragma unroll
      for (int reg = 0; reg < 4; reg++) {
        const int r = m0 + wm * 32 + ti * 16 + q * 4 + reg;
        float v = acc[ti][tj][reg] + bv;
        if (relu) v = fmaxf(v, 0.0f);
        if (out_f32) ((float*)Y)[(size_t)r * N + cc] = v;
        else ((unsigned short*)Y)[(size_t)r * N + cc] = f2bf(v);
      }
    }
}

// -------- mega-fused: layer-4 GEMM -> MFMA score -> softmax+fuse -> VQ -> norm ----
// 16 batch rows per block, 1024 threads (16 waves) for latency hiding at 1
// block/CU. L4/score are 24 wave-tasks over 16 waves; VQ gives each wave 32
// codewords. Same MFMA ordering / tie-breaks as the 512-thread version ->
// bit-identical results.
__global__ __launch_bounds__(1024) void l4vq_kernel(
    const unsigned short* __restrict__ h3b, const unsigned short* __restrict__ w4tb,
    const float* __restrict__ b4, const unsigned short* __restrict__ qw1tb,
    const float* __restrict__ qb1, const float* __restrict__ qw2,
    const float* __restrict__ cb, const unsigned short* __restrict__ cbb,
    const float* __restrict__ cbn2,
    unsigned short* __restrict__ zb, float* __restrict__ pos) {
  const int b0 = blockIdx.x * 16;
  const int t = threadIdx.x;
  const int w = t >> 6, lane = t & 63;
  const int ln = lane & 15, q = lane >> 4;
  const int colg = w & 7;

  __shared__ unsigned short h3s[48][264]; // h3 rows bf16 (padded)        (25.3 KB)
  __shared__ float e[48][D_];             // emb rows f32, r = s*16+bi    (24 KB)
  __shared__ unsigned short ebb[48][136]; // emb rows bf16 (padded)       (12.75 KB)
  __shared__ float qf[16][D_];            // fused -> qsum -> z1          (8 KB)
  __shared__ float resv[16][D_];          // residual f32                 (8 KB)
  __shared__ unsigned short resb[16][136];// residual bf16 (padded)       (4.25 KB)
  __shared__ float red2[8][48];
  __shared__ float sc[48];
  __shared__ float candd[16][16];
  __shared__ int candk[16][16];
  __shared__ int bestk[16];

  // qw1^T fragments for this wave's col-group (global, L2-hot)
  bf16x8 bq[4];
  {
    const unsigned short* qp = qw1tb + (size_t)(colg * 16 + ln) * D_;
#pragma unroll
    for (int ks = 0; ks < 4; ks++)
      bq[ks] = *(const bf16x8*)(qp + ks * 32 + q * 8);
  }

  // ---- stage h3 rows (48 x 256 bf16 = 1536 fragments of 8) ----
#pragma unroll
  for (int p = 0; p < 2; p++) {
    int f = p * 1024 + t;
    if (f < 1536) {
      int r = f >> 5, kf = f & 31;
      int s = r >> 4, bi = r & 15;
      *(bf16x8*)&h3s[r][kf * 8] =
          *(const bf16x8*)(h3b + ((size_t)(s * B_ + b0 + bi)) * H3_ + kf * 8);
    }
  }
  __syncthreads();

  // ---- layer-4 GEMM: 24 tasks (s x 8 col-groups) over 16 waves ----
#pragma unroll
  for (int i = 0; i < 2; i++) {
    int tk = w + 16 * i;
    if (tk < 24) {
      const int s = tk >> 3;
      const int col = (tk & 7) * 16 + ln;
      f32x4 oacc = (f32x4){0.f, 0.f, 0.f, 0.f};
      const unsigned short* wp = w4tb + ((size_t)(s * D_ + col)) * H3_;
#pragma unroll
      for (int ks = 0; ks < 8; ks++) {
        bf16x8 bfrag = *(const bf16x8*)(wp + ks * 32 + q * 8);
        bf16x8 afrag = *(const bf16x8*)&h3s[s * 16 + ln][ks * 32 + q * 8];
        oacc = __builtin_amdgcn_mfma_f32_16x16x32_bf16(afrag, bfrag, oacc, 0, 0, 0);
      }
      const float bv = b4[s * D_ + col];
#pragma unroll
      for (int reg = 0; reg < 4; reg++) {
        int r = s * 16 + q * 4 + reg;
        float v = oacc[reg] + bv;
        e[r][col] = v;
        ebb[r][col] = f2bf(v);
      }
    }
  }
  __syncthreads();

  // ---- attention scores via MFMA: 24 tasks (rt x 8 col-groups) ----
#pragma unroll
  for (int i = 0; i < 2; i++) {
    int tk = w + 16 * i;
    if (tk < 24) {
      const int rt = tk >> 3;            // tk&7 == colg for both tasks of a wave
      f32x4 sacc = (f32x4){0.f, 0.f, 0.f, 0.f};
#pragma unroll
      for (int ks = 0; ks < 4; ks++) {
        bf16x8 a = *(const bf16x8*)&ebb[rt * 16 + ln][ks * 32 + q * 8];
        sacc = __builtin_amdgcn_mfma_f32_16x16x32_bf16(a, bq[ks], sacc, 0, 0, 0);
      }
      const int col = colg * 16 + ln;
      const float qb = qb1[col], q2v = qw2[col];
#pragma unroll
      for (int reg = 0; reg < 4; reg++) {
        float v = tanhf(sacc[reg] + qb) * q2v;
#pragma unroll
        for (int off = 8; off > 0; off >>= 1) v += __shfl_xor(v, off, 16);
        if (ln == 0) red2[colg][rt * 16 + q * 4 + reg] = v;
      }
    }
  }
  __syncthreads();
  if (t < 48) {
    float s = 0.f;
#pragma unroll
    for (int g = 0; g < 8; g++) s += red2[g][t];
    sc[t] = s;                                 // sc[r], r = s*16+bi
  }
  __syncthreads();

  // ---- softmax over sources + fuse -> residual buffers (2048 elems) ----
#pragma unroll
  for (int p = 0; p < 2; p++) {
    int idx = p * 1024 + t;
    int bi = idx >> 7, dd = idx & 127;
    float s0 = sc[bi], s1 = sc[16 + bi], s2 = sc[32 + bi];
    float mx = fmaxf(s0, fmaxf(s1, s2));
    float e0 = __expf(s0 - mx), e1 = __expf(s1 - mx), e2 = __expf(s2 - mx);
    float inv = 1.0f / (e0 + e1 + e2);
    float fv = (e0 * e[bi][dd] + e1 * e[16 + bi][dd] + e2 * e[32 + bi][dd]) * inv;
    qf[bi][dd] = fv;
    resv[bi][dd] = fv;
    resb[bi][dd] = f2bf(fv);
  }
  __syncthreads();

  // ---- residual VQ (MFMA distance GEMM), 3 codebooks; 32 codewords/wave ----
  for (int c = 0; c < C_; c++) {
    bf16x8 a[4];
#pragma unroll
    for (int ks = 0; ks < 4; ks++)
      a[ks] = *(const bf16x8*)&resb[ln][ks * 32 + q * 8];
    f32x4 acc[2];
#pragma unroll
    for (int tt = 0; tt < 2; tt++) acc[tt] = (f32x4){0.f, 0.f, 0.f, 0.f};
#pragma unroll
    for (int tt = 0; tt < 2; tt++) {
      const int n = w * 32 + tt * 16 + ln;
      const unsigned short* bp = cbb + ((size_t)c * K_ + n) * D_;
#pragma unroll
      for (int ks = 0; ks < 4; ks++) {
        bf16x8 b = *(const bf16x8*)(bp + ks * 32 + q * 8);
        acc[tt] = __builtin_amdgcn_mfma_f32_16x16x32_bf16(a[ks], b, acc[tt], 0, 0, 0);
      }
    }
    float bd[4]; int bk[4];
#pragma unroll
    for (int reg = 0; reg < 4; reg++) { bd[reg] = 3.4e38f; bk[reg] = 0x7fffffff; }
#pragma unroll
    for (int tt = 0; tt < 2; tt++) {
      const int col = w * 32 + tt * 16 + ln;
      const float n2 = cbn2[c * K_ + col];
#pragma unroll
      for (int reg = 0; reg < 4; reg++) {
        float dist = n2 - 2.0f * acc[tt][reg];
        if (dist < bd[reg] || (dist == bd[reg] && col < bk[reg])) { bd[reg] = dist; bk[reg] = col; }
      }
    }
#pragma unroll
    for (int reg = 0; reg < 4; reg++) {
#pragma unroll
      for (int off = 8; off > 0; off >>= 1) {
        float d1 = __shfl_down(bd[reg], off, 16);
        int k1 = __shfl_down(bk[reg], off, 16);
        if (d1 < bd[reg] || (d1 == bd[reg] && k1 < bk[reg])) { bd[reg] = d1; bk[reg] = k1; }
      }
      if (ln == 0) { candd[w][q * 4 + reg] = bd[reg]; candk[w][q * 4 + reg] = bk[reg]; }
    }
    __syncthreads();
    if (w == 0) {
      int row = lane >> 2, g = lane & 3;
      float d0 = candd[g * 4][row]; int k0 = candk[g * 4][row];
#pragma unroll
      for (int j = 1; j < 4; j++) {
        float d1 = candd[g * 4 + j][row]; int k1 = candk[g * 4 + j][row];
        if (d1 < d0 || (d1 == d0 && k1 < k0)) { d0 = d1; k0 = k1; }
      }
#pragma unroll
      for (int off = 2; off > 0; off >>= 1) {
        float dn = __shfl_down(d0, off, 4);
        int kn = __shfl_down(k0, off, 4);
        if (dn < d0 || (dn == d0 && kn < k0)) { d0 = dn; k0 = kn; }
      }
      if (g == 0) bestk[row] = k0;
    }
    __syncthreads();
    {
      int idx = t * 2;
      int r = idx >> 7, dd = idx & 127;
      float2 qv = *(const float2*)(cb + ((size_t)c * K_ + bestk[r]) * D_ + dd);
      float2 rv = *(float2*)&resv[r][dd];
      rv.x -= qv.x; rv.y -= qv.y;
      *(float2*)&resv[r][dd] = rv;
      resb[r][dd + 0] = f2bf(rv.x); resb[r][dd + 1] = f2bf(rv.y);
    }
    __syncthreads();
  }

  // ---- qsum = fused - res (in LDS) ----
  {
    int idx = t * 2;
    int r = idx >> 7, dd = idx & 127;
    float2 f = *(float2*)&qf[r][dd];
    float2 rv = *(float2*)&resv[r][dd];
    f.x -= rv.x; f.y -= rv.y;
    *(float2*)&qf[r][dd] = f;
  }
  __syncthreads();

  // ---- z1 = normalize(qsum): 16 waves x 1 row ----
  {
    int r = w;
    float2 v = *(const float2*)&qf[r][lane * 2];
    float n2 = waveXorSum(v.x * v.x + v.y * v.y);
    float inv = 1.0f / fmaxf(sqrtf(n2), EPS_);
    float zx = v.x * inv, zy = v.y * inv;
    zb[(size_t)(b0 + r) * D_ + lane * 2 + 0] = f2bf(zx);
    zb[(size_t)(b0 + r) * D_ + lane * 2 + 1] = f2bf(zy);
    qf[r][lane * 2] = zx; qf[r][lane * 2 + 1] = zy;   // keep z1 f32 for pos
  }
  __syncthreads();

  // ---- z2 = normalize(emb) + pos = z1.z2: 16 waves x 3 rows ----
#pragma unroll
  for (int rr = 0; rr < 3; rr++) {
    int r = w * 3 + rr;                   // 0..47
    int s = r >> 4, bi = r & 15;
    float2 v = *(const float2*)&e[r][lane * 2];
    float n2 = waveXorSum(v.x * v.x + v.y * v.y);
    float inv = 1.0f / fmaxf(sqrtf(n2), EPS_);
    float zx = v.x * inv, zy = v.y * inv;
    size_t gb = (size_t)(1 + s) * B_ + b0 + bi;
    zb[gb * D_ + lane * 2 + 0] = f2bf(zx);
    zb[gb * D_ + lane * 2 + 1] = f2bf(zy);
    float2 a1 = *(const float2*)&qf[bi][lane * 2];
    float dsum = waveXorSum(a1.x * zx + a1.y * zy);
    if (lane == 0) pos[s * B_ + b0 + bi] = dsum;
  }
}

// ---------------- contrastive exp-rowsums: LDS-staged B tiles, JC_=8 ------------
__global__ __launch_bounds__(256) void contrast_mfma_kernel(
    const unsigned short* __restrict__ zb, float* __restrict__ rsP) {
  const int jc = blockIdx.x, ib = blockIdx.y, m = blockIdx.z;
  const int t = threadIdx.x;
  const int w = t >> 6, lane = t & 63;
  const int ln = lane & 15, q = lane >> 4;
  const int i0 = ib * 128 + w * 32;
  const unsigned short* Za = zb;
  const unsigned short* Zm = zb + (size_t)m * B_ * D_;
  const int JROWS = B_ / JC_;             // 512 j-rows per block
  const int NJT = JROWS / 64;             // 8 tiles

  __shared__ unsigned short Zsm[64 * 136];

  bf16x8 a[2][4];
#pragma unroll
  for (int si = 0; si < 2; si++)
#pragma unroll
    for (int ks = 0; ks < 4; ks++)
      a[si][ks] = *(const bf16x8*)(Za + (size_t)(i0 + si * 16 + ln) * D_ + ks * 32 + q * 8);

  const unsigned short* tb = Zm + (size_t)(jc * JROWS) * D_;
  bf16x8 rz[4];
#pragma unroll
  for (int p = 0; p < 4; p++)
    rz[p] = *(const bf16x8*)(tb + t * 8 + p * 2048);

  float e[2][4] = {};
  for (int jt = 0; jt < NJT; jt++) {
#pragma unroll
    for (int p = 0; p < 4; p++) {
      int c = t + p * 256;
      *(bf16x8*)&Zsm[(c >> 4) * 136 + (c & 15) * 8] = rz[p];
    }
    __syncthreads();
    if (jt + 1 < NJT) {
      const unsigned short* tn = Zm + (size_t)(jc * JROWS + (jt + 1) * 64) * D_;
#pragma unroll
      for (int p = 0; p < 4; p++)
        rz[p] = *(const bf16x8*)(tn + t * 8 + p * 2048);
    }
    f32x4 acc[2][4];
#pragma unroll
    for (int si = 0; si < 2; si++)
#pragma unroll
      for (int tj = 0; tj < 4; tj++) acc[si][tj] = (f32x4){0.f, 0.f, 0.f, 0.f};
#pragma unroll
    for (int tj = 0; tj < 4; tj++) {
      bf16x8 b[4];
#pragma unroll
      for (int ks = 0; ks < 4; ks++)
        b[ks] = *(const bf16x8*)&Zsm[(tj * 16 + ln) * 136 + ks * 32 + q * 8];
#pragma unroll
      for (int ks = 0; ks < 4; ks++) {
        acc[0][tj] = __builtin_amdgcn_mfma_f32_16x16x32_bf16(a[0][ks], b[ks], acc[0][tj], 0, 0, 0);
        acc[1][tj] = __builtin_amdgcn_mfma_f32_16x16x32_bf16(a[1][ks], b[ks], acc[1][tj], 0, 0, 0);
      }
    }
#pragma unroll
    for (int si = 0; si < 2; si++)
#pragma unroll
      for (int reg = 0; reg < 4; reg++) {
        float s = 0.f;
#pragma unroll
        for (int tj = 0; tj < 4; tj++) s += __expf(acc[si][tj][reg] * INV_T);
        e[si][reg] += s;
      }
    __syncthreads();
  }
#pragma unroll
  for (int si = 0; si < 2; si++)
#pragma unroll
    for (int reg = 0; reg < 4; reg++) {
#pragma unroll
      for (int off = 8; off > 0; off >>= 1)
        e[si][reg] += __shfl_xor(e[si][reg], off, 16);
    }
  if (ln == 0) {
#pragma unroll
    for (int si = 0; si < 2; si++)
#pragma unroll
      for (int reg = 0; reg < 4; reg++)
        rsP[((size_t)m * JC_ + jc) * B_ + i0 + si * 16 + q * 4 + reg] = e[si][reg];
  }
}

// ---------------- fused loss reduce + finalize (4 blocks) ----------------
__global__ __launch_bounds__(256) void final2_kernel(const float* __restrict__ rsP,
                                                     const float* __restrict__ pos,
                                                     const float* __restrict__ cbsumP,
                                                     float* __restrict__ out) {
  const int blk = blockIdx.x;
  const int t = threadIdx.x;
  __shared__ float red[4];
  if (blk == 0) {
    float acc = 0.0f;
    if (t < D_) {
#pragma unroll
      for (int m = 0; m < C_; m++) {
        float v = 0.0f;
#pragma unroll
        for (int b8 = 0; b8 < 8; b8++) v += cbsumP[(size_t)(m * 8 + b8) * D_ + t];
        acc += v * v;
      }
    }
    float v = waveReduceSum(acc);
    if ((t & 63) == 0) red[t >> 6] = v;
    __syncthreads();
    if (t == 0) {
      out[0] = (red[0] + red[1] + red[2] + red[3]) * (1.0f / (3.0f * 512.0f * 512.0f));
      out[1] = 0.0f;
    }
  } else {
    const int s = blk - 1;
    float acc = 0.0f;
    for (int it = 0; it < 16; it++) {
      const int i = it * 256 + t;
      float denom = -EXP10;
#pragma unroll
      for (int jc = 0; jc < JC_; jc++) {
        denom += rsP[(size_t)jc * B_ + i];
        denom += rsP[((size_t)(1 + s) * JC_ + jc) * B_ + i];
      }
      acc += logf(denom) - pos[s * B_ + i] * INV_T;
    }
    float v = waveReduceSum(acc);
    if ((t & 63) == 0) red[t >> 6] = v;
    __syncthreads();
    if (t == 0)
      out[2 + s] = (red[0] + red[1] + red[2] + red[3]) * (1.0f / 4096.0f);
  }
}

extern "C" void kernel_launch(void* const* d_in, const int* in_sizes, int n_in,
                              void* d_out, int out_size, void* d_ws, size_t ws_size,
                              hipStream_t stream) {
  const float* x    = (const float*)d_in[0];
  const float* w1   = (const float*)d_in[1];
  const float* b1   = (const float*)d_in[2];
  const float* w2   = (const float*)d_in[3];
  const float* b2   = (const float*)d_in[4];
  const float* w3   = (const float*)d_in[5];
  const float* b3   = (const float*)d_in[6];
  const float* w4   = (const float*)d_in[7];
  const float* b4   = (const float*)d_in[8];
  const float* qw1  = (const float*)d_in[9];
  const float* qb1  = (const float*)d_in[10];
  const float* qw2  = (const float*)d_in[11];
  const float* cb   = (const float*)d_in[12];
  float* out = (float*)d_out;
  char* base = (char*)d_ws;

  size_t o = 0;
  auto alloc = [&](size_t bytes) { size_t r = o; o += (bytes + 255) & ~(size_t)255; return r; };
  size_t o_xb   = alloc((size_t)S_ * B_ * DIN_ * 2);
  size_t o_wt1  = alloc((size_t)S_ * H1_ * DIN_ * 2);
  size_t o_wt2  = alloc((size_t)S_ * H2_ * H1_ * 2);
  size_t o_wt3  = alloc((size_t)S_ * H3_ * H2_ * 2);
  size_t o_w4t  = alloc((size_t)S_ * D_ * H3_ * 2);
  size_t o_h1b  = alloc((size_t)S_ * B_ * H1_ * 2);
  size_t o_h2b  = alloc((size_t)S_ * B_ * H2_ * 2);
  size_t o_h3b  = alloc((size_t)S_ * B_ * H3_ * 2);
  size_t o_zb   = alloc((size_t)4 * B_ * D_ * 2);
  size_t o_cbn2 = alloc((size_t)C_ * K_ * 4);
  size_t o_cbb  = alloc((size_t)C_ * K_ * D_ * 2);
  size_t o_rsP  = alloc((size_t)4 * JC_ * B_ * 4);
  size_t o_cbsP = alloc((size_t)C_ * 8 * D_ * 4);
  size_t o_pos  = alloc((size_t)S_ * B_ * 4);
  size_t o_q1t  = alloc((size_t)D_ * D_ * 2);
  (void)ws_size; (void)in_sizes; (void)n_in; (void)out_size;

  unsigned short* xb  = (unsigned short*)(base + o_xb);
  unsigned short* wt1 = (unsigned short*)(base + o_wt1);
  unsigned short* wt2 = (unsigned short*)(base + o_wt2);
  unsigned short* wt3 = (unsigned short*)(base + o_wt3);
  unsigned short* w4tb= (unsigned short*)(base + o_w4t);
  unsigned short* h1b = (unsigned short*)(base + o_h1b);
  unsigned short* h2b = (unsigned short*)(base + o_h2b);
  unsigned short* h3b = (unsigned short*)(base + o_h3b);
  unsigned short* zb = (unsigned short*)(base + o_zb);
  float* cbn2  = (float*)(base + o_cbn2);
  unsigned short* cbb = (unsigned short*)(base + o_cbb);
  float* rsP   = (float*)(base + o_rsP);
  float* cbsumP= (float*)(base + o_cbsP);
  float* pos   = (float*)(base + o_pos);
  unsigned short* qw1tb = (unsigned short*)(base + o_q1t);

  // fused prep: x->bf16 + weight transposes + codebook norms + qw1^T (one launch)
  const int prep_blocks = (S_ * B_ * DIN_) / 1024 + 1536 + 576 + 288 + 96 + C_ * 8 + 16;
  prep_kernel<<<dim3(prep_blocks), 256, 0, stream>>>(x, xb, w1, wt1, w2, wt2, w3, wt3, w4, w4tb,
                                                     cb, cbn2, cbsumP, cbb, qw1, qw1tb);

  // encoder MLP layers 1-3 via LDS-staged MFMA (BK=64, async B staging)
  const int Mtot = S_ * B_;
  gemm_lds_kernel<<<dim3(H1_ / 128, Mtot / 64), 256, 0, stream>>>(xb, wt1, b1, h1b, DIN_, H1_, 1, 0);
  gemm_lds_kernel<<<dim3(H2_ / 128, Mtot / 64), 256, 0, stream>>>(h1b, wt2, b2, h2b, H1_, H2_, 1, 0);
  gemm_lds_kernel<<<dim3(H3_ / 128, Mtot / 64), 256, 0, stream>>>(h2b, wt3, b3, h3b, H2_, H3_, 1, 0);

  // mega-fused: layer-4 GEMM -> MFMA score -> softmax+fuse -> VQ -> normalize+pos
  // 16 rows/block, 1024 threads (16 waves) for latency hiding
  l4vq_kernel<<<dim3(B_ / 16), 1024, 0, stream>>>(h3b, w4tb, b4, qw1tb, qb1, qw2,
                                                  cb, cbb, cbn2, zb, pos);

  // contrastive rowsum partials (JC_=8 -> 1024 blocks -> 4 blocks/CU)
  contrast_mfma_kernel<<<dim3(JC_, 32, 4), 256, 0, stream>>>(zb, rsP);

  // fused loss reduce + finalize
  final2_kernel<<<dim3(4), 256, 0, stream>>>(rsP, pos, cbsumP, out);
}